// Round 15
// baseline (358.851 us; speedup 1.0000x reference)
//
#include <hip/hip_runtime.h>
#include <stdint.h>

// ---------------------------------------------------------------------------
// MixedSparseSingleLayerWithGate: NF4-dequant QLoRA transformer layer, MI355X.
// R15: per-operand stride tuning — A-side (activations h/obf/hb) on x128B
// strides (row cacheline alignment: R11 evidence), B-side (weights) on odd
// x64B strides (L2 channel de-alias: R13 evidence). K/V rope_pack rewritten
// as LDS tile transposes (kills the 6KB-stride 8-way scatter).
//   h,obf: 1088 | W_qkv,W_o: 1120 | W_gu: 1056 | hb: 2880 | W_d: 2912
// ---------------------------------------------------------------------------

#define Sq   2048
#define Dm   1024
#define Fm   2816
#define Hh   16
#define LHA  1088   // h & obf stride (2176B = 17x128, A-side aligned)
#define LWQ  1120   // W_qkv & W_o stride (2240B = 35x64, odd B-side)
#define KQ   1088   // qkv & o GEMM reduction
#define LGU  1056   // gate/up W stride and reduction (2112B = 33x64 odd)
#define LHB  2880   // hb stride (5760B = 45x128, A-side aligned)
#define LWD  2912   // W_down stride (5824B = 91x64, odd B-side)
#define KD   2880   // down GEMM reduction
#define NQKV 3072
#define NGU  5632

typedef short bf16x8 __attribute__((ext_vector_type(8)));
typedef float f32x4  __attribute__((ext_vector_type(4)));

__constant__ float NF4_LUT[16] = {
    -1.0f, -0.6961928009986877f, -0.5250730514526367f, -0.39491748809814453f,
    -0.28444138169288635f, -0.18477343022823334f, -0.09105003625154495f, 0.0f,
    0.07958029955625534f, 0.16093020141124725f, 0.24611230194568634f,
    0.33791524171829224f, 0.44070982933044434f, 0.5626170039176941f,
    0.7229568362236023f, 1.0f};

__device__ inline unsigned short f2bf(float f) {
    union { float f; uint32_t u; } v; v.f = f;
    uint32_t u = v.u;
    return (unsigned short)((u + 0x7FFFu + ((u >> 16) & 1u)) >> 16);
}
__device__ inline float bf2f(unsigned short h) {
    union { uint32_t u; float f; } v; v.u = ((uint32_t)h) << 16;
    return v.f;
}
__device__ inline unsigned short truncbf(float f) {
    union { float f; uint32_t u; } v; v.f = f;
    return (unsigned short)(v.u >> 16);
}

// async global->LDS, 16 B per lane; LDS dest = wave-uniform base + lane*16
#define GLD16(gp, lp)                                                         \
    __builtin_amdgcn_global_load_lds(                                         \
        (__attribute__((address_space(1))) void*)(uintptr_t)(gp),             \
        (__attribute__((address_space(3))) void*)(uint32_t)(uintptr_t)(lp),   \
        16, 0, 0)

// --------------------------- rmsnorm -> bf16 ext -----------------------------
__global__ __launch_bounds__(256) void rmsnorm_ext(
    const float* __restrict__ X, const float* __restrict__ W,
    unsigned short* Hout, int ldh)
{
    int s = blockIdx.x, tid = threadIdx.x;
    const float4 v = *(const float4*)(X + (size_t)s * Dm + tid * 4);
    float ss = v.x * v.x + v.y * v.y + v.z * v.z + v.w * v.w;
#pragma unroll
    for (int m = 1; m < 64; m <<= 1) ss += __shfl_xor(ss, m);
    __shared__ float red[4];
    int lane = tid & 63, wave = tid >> 6;
    if (lane == 0) red[wave] = ss;
    __syncthreads();
    float scale = rsqrtf((red[0] + red[1] + red[2] + red[3]) * (1.0f / Dm) + 1e-10f);
    const float4 w = *(const float4*)(W + tid * 4);
    alignas(8) unsigned short o[4];
    o[0] = f2bf(v.x * scale * w.x);
    o[1] = f2bf(v.y * scale * w.y);
    o[2] = f2bf(v.z * scale * w.z);
    o[3] = f2bf(v.w * scale * w.w);
    *(ushort4*)(Hout + (size_t)s * ldh + tid * 4) = *(ushort4*)o;
    if (tid < 64) Hout[(size_t)s * ldh + Dm + tid] = 0;   // zero 1024..1088
}

// -------- pack la matrices into MFMA B-fragment chunks (bf16) ---------------
__global__ __launch_bounds__(256) void lora_prep(
    const float* __restrict__ qla, const float* __restrict__ kla,
    const float* __restrict__ vla, const float* __restrict__ ola,
    const float* __restrict__ gla, const float* __restrict__ ula,
    const float* __restrict__ dla, unsigned short* __restrict__ lapk)
{
    int tid = threadIdx.x;
    int chunk = blockIdx.x * 4 + (tid >> 6);
    int lane = tid & 63;
    int lr = lane & 15, quad = lane >> 4;
    const float* la;
    int lc;
    if (chunk < 192) {
        int m = chunk >> 5; lc = chunk & 31;
        la = (m == 0) ? qla : (m == 1) ? kla : (m == 2) ? vla
           : (m == 3) ? ola : (m == 4) ? gla : ula;
    } else {
        la = dla; lc = chunk - 192;
    }
    alignas(16) unsigned short out[8];
#pragma unroll
    for (int e = 0; e < 8; ++e)
        out[e] = f2bf(la[(size_t)(lc * 32 + quad * 8 + e) * 16 + lr]);
    *(uint4*)(lapk + (size_t)chunk * 512 + lane * 8) = *(uint4*)out;
}

// -------- T = A @ la via MFMA; 16-row strips, 4-way wave K-split ------------
template<int NM>
__global__ __launch_bounds__(256) void lora_mfma(
    unsigned short* Aext, int lda, int K,
    const unsigned short* __restrict__ lapk, int c0, int c1, int c2,
    int toff, int zoff, int zn)
{
    int tid = threadIdx.x;
    int lane = tid & 63, wave = tid >> 6;
    int lr = lane & 15, quad = lane >> 4;
    int r0 = blockIdx.x * 16;
    int nc4 = K >> 7;                       // chunks per wave
    int gc0 = wave * nc4;
    const unsigned short* Ab = Aext + (size_t)(r0 + lr) * lda + quad * 8;
    int cb[3] = {c0, c1, c2};
    f32x4 zero = {0.f, 0.f, 0.f, 0.f};
    f32x4 acc[NM];
#pragma unroll
    for (int m = 0; m < NM; ++m) acc[m] = zero;
    for (int cc = 0; cc < nc4; ++cc) {
        int gc = gc0 + cc;
        bf16x8 af = *(const bf16x8*)(Ab + gc * 32);
#pragma unroll
        for (int m = 0; m < NM; ++m) {
            bf16x8 bf = *(const bf16x8*)(lapk + (size_t)(cb[m] + gc) * 512 + lane * 8);
            acc[m] = __builtin_amdgcn_mfma_f32_16x16x32_bf16(af, bf, acc[m], 0, 0, 0);
        }
    }
    __shared__ float red[3][NM * 64 * 4];
    if (wave > 0) {
#pragma unroll
        for (int m = 0; m < NM; ++m)
#pragma unroll
            for (int r = 0; r < 4; ++r)
                red[wave - 1][(m * 64 + lane) * 4 + r] = acc[m][r];
    }
    __syncthreads();
    if (wave == 0) {
#pragma unroll
        for (int m = 0; m < NM; ++m)
#pragma unroll
            for (int r = 0; r < 4; ++r)
                acc[m][r] += red[0][(m * 64 + lane) * 4 + r]
                           + red[1][(m * 64 + lane) * 4 + r]
                           + red[2][(m * 64 + lane) * 4 + r];
#pragma unroll
        for (int r = 0; r < 4; ++r) {
            int row = r0 + quad * 4 + r;
#pragma unroll
            for (int m = 0; m < NM; ++m)
                Aext[(size_t)row * lda + toff + m * 16 + lr] = f2bf(acc[m][r]);
        }
        if (zn > 0) {
            int row = r0 + lr, j0 = quad * 4;
            for (int j = j0; j < zn; j += 64) {
                alignas(8) unsigned short z4[4] = {0, 0, 0, 0};
                *(ushort4*)(Aext + (size_t)row * lda + zoff + j) = *(ushort4*)z4;
            }
        }
    }
}

// ---------------- NF4 dequant helpers (bf16, K-extended rows) ---------------
__device__ inline void dq_row8(const float* lut, const int* cod, const float* am,
                               const float* lb, int nr, int c8, int K, int Nlb,
                               int toff, unsigned short* out)
{
    if (c8 < K) {
        size_t base = (size_t)nr * K + c8;
        const int4* cp = (const int4*)(cod + base);
        int4 ca = cp[0], cb = cp[1];
        float a = am[base >> 6];
        out[0] = f2bf(lut[ca.x] * a); out[1] = f2bf(lut[ca.y] * a);
        out[2] = f2bf(lut[ca.z] * a); out[3] = f2bf(lut[ca.w] * a);
        out[4] = f2bf(lut[cb.x] * a); out[5] = f2bf(lut[cb.y] * a);
        out[6] = f2bf(lut[cb.z] * a); out[7] = f2bf(lut[cb.w] * a);
    } else {
        int r = c8 - toff;
#pragma unroll
        for (int i = 0; i < 8; ++i) out[i] = 0;
        if (r >= 0 && r < 16) {
#pragma unroll
            for (int i = 0; i < 8; ++i) out[i] = f2bf(lb[(size_t)(r + i) * Nlb + nr]);
        }
    }
}

// q/k/v fused: W rows [0,1024)=q, [1024,2048)=k, [2048,3072)=v ; ldw=LWQ
__global__ __launch_bounds__(256) void dequant_qkv(
    const int* __restrict__ qc, const int* __restrict__ kc, const int* __restrict__ vc,
    const float* __restrict__ qa, const float* __restrict__ ka, const float* __restrict__ va,
    const float* __restrict__ qlb, const float* __restrict__ klb, const float* __restrict__ vlb,
    unsigned short* __restrict__ Wout)
{
    __shared__ float lut[16];
    if (threadIdx.x < 16) lut[threadIdx.x] = NF4_LUT[threadIdx.x];
    __syncthreads();
    int idx = blockIdx.x * 256 + threadIdx.x;        // 3072*140
    int n = idx / 140;
    int c8 = (idx - n * 140) * 8;
    int seg = n >> 10, nr = n & 1023;
    const int* cod   = (seg == 0) ? qc : (seg == 1) ? kc : vc;
    const float* am  = (seg == 0) ? qa : (seg == 1) ? ka : va;
    const float* lb  = (seg == 0) ? qlb : (seg == 1) ? klb : vlb;
    int toff = 1024 + (seg << 4);
    alignas(16) unsigned short out[8];
    dq_row8(lut, cod, am, lb, nr, c8, 1024, 1024, toff, out);
    *(uint4*)(Wout + (size_t)n * LWQ + c8) = *(uint4*)out;
}

// gate/up fused + interleaved: stride LGU (132 chunks)
__global__ __launch_bounds__(256) void dequant_gu(
    const int* __restrict__ gc, const int* __restrict__ uc,
    const float* __restrict__ ga, const float* __restrict__ ua,
    const float* __restrict__ glb, const float* __restrict__ ulb,
    unsigned short* __restrict__ Wout)
{
    __shared__ float lut[16];
    if (threadIdx.x < 16) lut[threadIdx.x] = NF4_LUT[threadIdx.x];
    __syncthreads();
    int idx = blockIdx.x * 256 + threadIdx.x;        // 5632*132
    int n = idx / 132;
    int c8 = (idx - n * 132) * 8;
    int m = n >> 1, mat = n & 1;
    const int* cod  = mat ? uc : gc;
    const float* am = mat ? ua : ga;
    const float* lb = mat ? ulb : glb;
    int toff = 1024 + (mat << 4);
    alignas(16) unsigned short out[8];
    dq_row8(lut, cod, am, lb, m, c8, 1024, Fm, toff, out);
    *(uint4*)(Wout + (size_t)n * LGU + c8) = *(uint4*)out;
}

// generic (o-proj, down)
__global__ __launch_bounds__(256) void dequant_ext(
    const int* __restrict__ codes, const float* __restrict__ absmax,
    const float* __restrict__ lb, unsigned short* __restrict__ Wout,
    int Nproj, int K, int ldw, int toff)
{
    __shared__ float lut[16];
    if (threadIdx.x < 16) lut[threadIdx.x] = NF4_LUT[threadIdx.x];
    __syncthreads();
    int idx = blockIdx.x * 256 + threadIdx.x;
    int cpr = ldw >> 3;
    int n = idx / cpr;
    if (n >= Nproj) return;
    int c8 = (idx - n * cpr) * 8;
    alignas(16) unsigned short out[8];
    dq_row8(lut, codes, absmax, lb, n, c8, K, Nproj, toff, out);
    *(uint4*)(Wout + (size_t)n * ldw + c8) = *(uint4*)out;
}

// ------------------- GEMM 128x128, dbuf, bf16-out (qkv) ---------------------
__global__ __launch_bounds__(256) void gemm128(
    const unsigned short* __restrict__ A, int lda,
    const unsigned short* __restrict__ B, int ldb, int K,
    unsigned short* __restrict__ Cb, int ldc)
{
    __shared__ __align__(16) unsigned short At[2][128 * 32];
    __shared__ __align__(16) unsigned short Bt[2][128 * 32];
    int tid = threadIdx.x;
    int lane = tid & 63, wave = tid >> 6;
    int lr = lane & 15, quad = lane >> 4;
    int wm = (wave >> 1) * 64, wn = (wave & 1) * 64;
    int row0 = blockIdx.y * 128, col0 = blockIdx.x * 128;
    f32x4 acc[4][4];
    f32x4 zero = {0.f, 0.f, 0.f, 0.f};
#pragma unroll
    for (int i = 0; i < 4; ++i)
#pragma unroll
        for (int j = 0; j < 4; ++j) acc[i][j] = zero;
    int sw = ((tid & 3) ^ ((tid >> 3) & 3)) * 8;
    const unsigned short* Ag  = A + (size_t)(row0 + (tid >> 2)) * lda + sw;
    const unsigned short* Ag2 = Ag + (size_t)64 * lda;
    const unsigned short* Bg  = B + (size_t)(col0 + (tid >> 2)) * ldb + sw;
    const unsigned short* Bg2 = Bg + (size_t)64 * ldb;
    int l0 = tid * 8, l1 = (tid + 256) * 8;
    GLD16(Ag, At[0] + l0); GLD16(Ag2, At[0] + l1);
    GLD16(Bg, Bt[0] + l0); GLD16(Bg2, Bt[0] + l1);
    int sq = (quad ^ ((lr >> 1) & 3)) * 8;
    int nIter = K >> 5;
    for (int it = 0; it < nIter; ++it) {
        int cur = it & 1;
        __syncthreads();
        if (it + 1 < nIter) {
            int k = (it + 1) << 5, nx = cur ^ 1;
            GLD16(Ag + k, At[nx] + l0); GLD16(Ag2 + k, At[nx] + l1);
            GLD16(Bg + k, Bt[nx] + l0); GLD16(Bg2 + k, Bt[nx] + l1);
        }
        bf16x8 af[4], bfr[4];
#pragma unroll
        for (int i = 0; i < 4; ++i)
            af[i] = *(const bf16x8*)(At[cur] + (wm + i * 16 + lr) * 32 + sq);
#pragma unroll
        for (int j = 0; j < 4; ++j)
            bfr[j] = *(const bf16x8*)(Bt[cur] + (wn + j * 16 + lr) * 32 + sq);
#pragma unroll
        for (int i = 0; i < 4; ++i)
#pragma unroll
            for (int j = 0; j < 4; ++j)
                acc[i][j] = __builtin_amdgcn_mfma_f32_16x16x32_bf16(af[i], bfr[j], acc[i][j], 0, 0, 0);
    }
#pragma unroll
    for (int i = 0; i < 4; ++i) {
        int rowb = row0 + wm + i * 16 + quad * 4;
#pragma unroll
        for (int j = 0; j < 4; ++j) {
            int col = col0 + wn + j * 16 + lr;
#pragma unroll
            for (int r = 0; r < 4; ++r)
                Cb[(size_t)(rowb + r) * ldc + col] = f2bf(acc[i][j][r]);
        }
    }
}

// ---------------- GEMM 128x128, dbuf, SwiGLU epilogue (gate/up) -------------
__global__ __launch_bounds__(256) void gemm_gu(
    const unsigned short* __restrict__ A, int lda,
    const unsigned short* __restrict__ B, int ldb, int K,
    unsigned short* __restrict__ Hb)
{
    __shared__ __align__(16) unsigned short At[2][128 * 32];
    __shared__ __align__(16) unsigned short Bt[2][128 * 32];
    int tid = threadIdx.x;
    int lane = tid & 63, wave = tid >> 6;
    int lr = lane & 15, quad = lane >> 4;
    int wm = (wave >> 1) * 64, wn = (wave & 1) * 64;
    int row0 = blockIdx.y * 128, col0 = blockIdx.x * 128;
    f32x4 acc[4][4];
    f32x4 zero = {0.f, 0.f, 0.f, 0.f};
#pragma unroll
    for (int i = 0; i < 4; ++i)
#pragma unroll
        for (int j = 0; j < 4; ++j) acc[i][j] = zero;
    int sw = ((tid & 3) ^ ((tid >> 3) & 3)) * 8;
    const unsigned short* Ag  = A + (size_t)(row0 + (tid >> 2)) * lda + sw;
    const unsigned short* Ag2 = Ag + (size_t)64 * lda;
    const unsigned short* Bg  = B + (size_t)(col0 + (tid >> 2)) * ldb + sw;
    const unsigned short* Bg2 = Bg + (size_t)64 * ldb;
    int l0 = tid * 8, l1 = (tid + 256) * 8;
    GLD16(Ag, At[0] + l0); GLD16(Ag2, At[0] + l1);
    GLD16(Bg, Bt[0] + l0); GLD16(Bg2, Bt[0] + l1);
    int sq = (quad ^ ((lr >> 1) & 3)) * 8;
    int nIter = K >> 5;
    for (int it = 0; it < nIter; ++it) {
        int cur = it & 1;
        __syncthreads();
        if (it + 1 < nIter) {
            int k = (it + 1) << 5, nx = cur ^ 1;
            GLD16(Ag + k, At[nx] + l0); GLD16(Ag2 + k, At[nx] + l1);
            GLD16(Bg + k, Bt[nx] + l0); GLD16(Bg2 + k, Bt[nx] + l1);
        }
        bf16x8 af[4], bfr[4];
#pragma unroll
        for (int i = 0; i < 4; ++i)
            af[i] = *(const bf16x8*)(At[cur] + (wm + i * 16 + lr) * 32 + sq);
#pragma unroll
        for (int j = 0; j < 4; ++j)
            bfr[j] = *(const bf16x8*)(Bt[cur] + (wn + j * 16 + lr) * 32 + sq);
#pragma unroll
        for (int i = 0; i < 4; ++i)
#pragma unroll
            for (int j = 0; j < 4; ++j)
                acc[i][j] = __builtin_amdgcn_mfma_f32_16x16x32_bf16(af[i], bfr[j], acc[i][j], 0, 0, 0);
    }
#pragma unroll
    for (int i = 0; i < 4; ++i) {
        int rowb = row0 + wm + i * 16 + quad * 4;
#pragma unroll
        for (int j = 0; j < 4; ++j) {
            int col = col0 + wn + j * 16 + lr;     // even=gate, odd=up
#pragma unroll
            for (int r = 0; r < 4; ++r) {
                float own = acc[i][j][r];
                float oth = __shfl_xor(own, 1);
                if (!(lr & 1)) {
                    float sig = 1.0f / (1.0f + __expf(-own));
                    Hb[(size_t)(rowb + r) * LHB + (col >> 1)] = f2bf(oth * own * sig);
                }
            }
        }
    }
}

// ------ GEMM 64x64, BK=64 dbuf, f32 + residual out (o, down) ----------------
template<int TAG>
__global__ __launch_bounds__(256) void gemm_s(
    const unsigned short* __restrict__ A, int lda,
    const unsigned short* __restrict__ B, int ldb, int K,
    float* __restrict__ Cf, int ldc, const float* __restrict__ Radd)
{
    __shared__ __align__(16) unsigned short At[2][64 * 64];
    __shared__ __align__(16) unsigned short Bt[2][64 * 64];
    int tid = threadIdx.x;
    int lane = tid & 63, wave = tid >> 6;
    int lr = lane & 15, quad = lane >> 4;
    int row0 = blockIdx.y * 64, col0 = blockIdx.x * 64;
    f32x4 acc[4];
    f32x4 zero = {0.f, 0.f, 0.f, 0.f};
#pragma unroll
    for (int j = 0; j < 4; ++j) acc[j] = zero;
    int rs = tid >> 3;
    int g8 = ((tid & 7) ^ (rs & 7)) * 8;
    const unsigned short* Ag  = A + (size_t)(row0 + rs) * lda + g8;
    const unsigned short* Ag2 = Ag + (size_t)32 * lda;
    const unsigned short* Bg  = B + (size_t)(col0 + rs) * ldb + g8;
    const unsigned short* Bg2 = Bg + (size_t)32 * ldb;
    int l0 = tid * 8, l1 = (tid + 256) * 8;
    GLD16(Ag, At[0] + l0); GLD16(Ag2, At[0] + l1);
    GLD16(Bg, Bt[0] + l0); GLD16(Bg2, Bt[0] + l1);
    int c0 = (quad ^ (lr & 7)) * 8;
    int c1 = ((4 + quad) ^ (lr & 7)) * 8;
    int nIter = K >> 6;
    for (int it = 0; it < nIter; ++it) {
        int cur = it & 1;
        __syncthreads();
        if (it + 1 < nIter) {
            int k = (it + 1) << 6, nx = cur ^ 1;
            GLD16(Ag + k, At[nx] + l0); GLD16(Ag2 + k, At[nx] + l1);
            GLD16(Bg + k, Bt[nx] + l0); GLD16(Bg2 + k, Bt[nx] + l1);
        }
        const unsigned short* arow = At[cur] + (wave * 16 + lr) * 64;
        bf16x8 a0 = *(const bf16x8*)(arow + c0);
        bf16x8 a1 = *(const bf16x8*)(arow + c1);
        bf16x8 b0[4], b1[4];
#pragma unroll
        for (int j = 0; j < 4; ++j) {
            const unsigned short* brow = Bt[cur] + (j * 16 + lr) * 64;
            b0[j] = *(const bf16x8*)(brow + c0);
            b1[j] = *(const bf16x8*)(brow + c1);
        }
#pragma unroll
        for (int j = 0; j < 4; ++j) {
            acc[j] = __builtin_amdgcn_mfma_f32_16x16x32_bf16(a0, b0[j], acc[j], 0, 0, 0);
            acc[j] = __builtin_amdgcn_mfma_f32_16x16x32_bf16(a1, b1[j], acc[j], 0, 0, 0);
        }
    }
    int rowb = row0 + wave * 16 + quad * 4;
#pragma unroll
    for (int j = 0; j < 4; ++j) {
        int col = col0 + j * 16 + lr;
#pragma unroll
        for (int r = 0; r < 4; ++r) {
            size_t o = (size_t)(rowb + r) * ldc + col;
            Cf[o] = acc[j][r] + Radd[o];
        }
    }
}

// --- fused rope(q) + LDS-tiled rope+pack(K) + LDS-tiled pack(V) -------------
// blocks 0..8191: Q rope (coalesced). 8192..8447: K (h,sb) 128-row tiles.
// 8448..8703: V (h,kt) 128-row tiles. All global accesses coalesced.
__global__ __launch_bounds__(256) void rope_pack(
    const unsigned short* __restrict__ qkv,
    const float* __restrict__ cosT, const float* __restrict__ sinT,
    const int* __restrict__ pos,
    unsigned short* __restrict__ qb, unsigned short* __restrict__ kpk,
    unsigned short* __restrict__ vpk)
{
    __shared__ __align__(16) unsigned short t[128][72];
    int b = blockIdx.x, tid = threadIdx.x;
    if (b < 8192) {                              // Q rope
        int idx = b * 256 + tid;                 // over 2048*1024
        int s = idx >> 10, col = idx & 1023, d = col & 63;
        int p = pos[s];
        float c = cosT[p * 64 + d], sn = sinT[p * 64 + d];
        int partner = (d < 32) ? (col + 32) : (col - 32);
        float sgn = (d < 32) ? -1.f : 1.f;
        const unsigned short* row = qkv + (size_t)s * NQKV;
        float q = bf2f(row[col]), q2 = bf2f(row[partner]);
        qb[idx] = f2bf((q * c + sgn * q2 * sn) * 0.125f);
    } else if (b < 8448) {                       // K rope + pack via LDS tile
        int bb = b - 8192;
        int h = bb >> 4, sb = bb & 15;           // 128 rows at s0
        int s0 = sb * 128;
#pragma unroll
        for (int p = 0; p < 4; ++p) {
            int flat = p * 256 + tid;
            int row = flat >> 3, c8 = (flat & 7) * 8;
            *(uint4*)&t[row][c8] =
                *(const uint4*)(qkv + (size_t)(s0 + row) * NQKV + Dm + h * 64 + c8);
        }
        __syncthreads();
        int lane = tid & 63, fw = tid >> 6;
        int lr = lane & 15, quad = lane >> 4;
#pragma unroll
        for (int ff = 0; ff < 4; ++ff) {
            int frag = fw * 4 + ff;              // 0..15
            int t16 = frag >> 1, c = frag & 1;
            int srow = t16 * 16 + lr;
            int p2 = pos[s0 + srow];
            int d0 = c * 32 + quad * 8;
            float sgn = (d0 < 32) ? -1.f : 1.f;
            const float* cp = cosT + p2 * 64 + d0;
            const float* sp = sinT + p2 * 64 + d0;
            alignas(16) unsigned short out[8];
#pragma unroll
            for (int e = 0; e < 8; ++e) {
                float kv = bf2f(t[srow][d0 + e]);
                float kq = bf2f(t[srow][(d0 + e) ^ 32]);
                out[e] = f2bf(kv * cp[e] + sgn * kq * sp[e]);
            }
            size_t fbase = ((size_t)(h * 128 + sb * 8 + t16) * 2 + c) * 512;
            *(uint4*)(kpk + fbase + lane * 8) = *(uint4*)out;
        }
    } else {                                     // V pack via LDS tile
        int bb = b - 8448;
        int h = bb >> 4, kt = bb & 15;           // 128 rows at s0
        int s0 = kt * 128;
#pragma unroll
        for (int p = 0; p < 4; ++p) {
            int flat = p * 256 + tid;
            int row = flat >> 3, c8 = (flat & 7) * 8;
            *(uint4*)&t[row][c8] =
                *(const uint4*)(qkv + (size_t)(s0 + row) * NQKV + 2048 + h * 64 + c8);
        }
        __syncthreads();
        int lane = tid & 63, fw = tid >> 6;
        int lr = lane & 15, quad = lane >> 4;
#pragma unroll
        for (int ff = 0; ff < 4; ++ff) {
            int frag = fw * 4 + ff;              // 0..15
            int j = frag >> 2, kk = frag & 3;
            alignas(16) unsigned short out[8];
#pragma unroll
            for (int e = 0; e < 8; ++e)
                out[e] = t[kk * 32 + quad * 8 + e][j * 16 + lr];
            size_t fbase = (size_t)(((h * 16 + kt) * 4 + j) * 4 + kk) * 512;
            *(uint4*)(vpk + fbase + lane * 8) = *(uint4*)out;
        }
    }
}

// ------------- flash attention: packed frags, no-max softmax ----------------
__global__ __launch_bounds__(256) void attn(
    const unsigned short* __restrict__ qb, const unsigned short* __restrict__ kpk,
    const unsigned short* __restrict__ vpk, unsigned short* __restrict__ ob)
{
    __shared__ __align__(16) unsigned short Ps[4][16 * 136];
    int tid = threadIdx.x;
    int lane = tid & 63, wave = tid >> 6;
    int lr = lane & 15, quad = lane >> 4;
    int idx = blockIdx.x;
    int t_ = idx >> 4;
    int qt = (idx < 256) ? (31 - t_) : (t_ - 16);
    int h = idx & 15;
    int r0 = qt * 64 + wave * 16;
    const unsigned short* qp = qb + (size_t)(r0 + lr) * Dm + h * 64 + quad * 8;
    bf16x8 qf0 = *(const bf16x8*)qp;
    bf16x8 qf1 = *(const bf16x8*)(qp + 32);
    const unsigned short* kpb = kpk + (size_t)h * 128 * 1024 + lane * 8;
    const unsigned short* vpb = vpk + (size_t)h * 16 * 16 * 512 + lane * 8;
    f32x4 zero = {0.f, 0.f, 0.f, 0.f};
    f32x4 oacc[4];
#pragma unroll
    for (int j = 0; j < 4; ++j) oacc[j] = zero;
    float lrow[4] = {0.f, 0.f, 0.f, 0.f};
    int ntile = (qt * 64 + 191) >> 7;

    for (int kt = 0; kt < ntile; ++kt) {
        int k0 = kt << 7;
        f32x4 sf[8];
#pragma unroll
        for (int jj = 0; jj < 8; ++jj) {
            const unsigned short* kp = kpb + (size_t)(kt * 8 + jj) * 1024;
            bf16x8 kf0 = *(const bf16x8*)kp;
            bf16x8 kf1 = *(const bf16x8*)(kp + 512);
            f32x4 z = zero;
            z = __builtin_amdgcn_mfma_f32_16x16x32_bf16(qf0, kf0, z, 0, 0, 0);
            z = __builtin_amdgcn_mfma_f32_16x16x32_bf16(qf1, kf1, z, 0, 0, 0);
            sf[jj] = z;
        }
        bf16x8 vf[4][4];
#pragma unroll
        for (int j = 0; j < 4; ++j)
#pragma unroll
            for (int kk = 0; kk < 4; ++kk)
                vf[j][kk] = *(const bf16x8*)(vpb + (size_t)((kt * 4 + j) * 4 + kk) * 512);
        if (kt == ntile - 1) {
#pragma unroll
            for (int jj = 0; jj < 8; ++jj)
#pragma unroll
                for (int r = 0; r < 4; ++r)
                    if (k0 + jj * 16 + lr > r0 + quad * 4 + r)
                        sf[jj][r] = -1e30f;
        }
#pragma unroll
        for (int jj = 0; jj < 8; ++jj)
#pragma unroll
            for (int r = 0; r < 4; ++r) {
                float p = __expf(sf[jj][r]);
                sf[jj][r] = p;
                lrow[r] += p;
            }
#pragma unroll
        for (int jj = 0; jj < 8; ++jj)
#pragma unroll
            for (int r = 0; r < 4; ++r)
                Ps[wave][(quad * 4 + r) * 136 + jj * 16 + lr] = truncbf(sf[jj][r]);
        bf16x8 pf[4];
#pragma unroll
        for (int kk = 0; kk < 4; ++kk)
            pf[kk] = *(const bf16x8*)(&Ps[wave][lr * 136 + kk * 32 + quad * 8]);
#pragma unroll
        for (int j = 0; j < 4; ++j)
#pragma unroll
            for (int kk = 0; kk < 4; ++kk)
                oacc[j] = __builtin_amdgcn_mfma_f32_16x16x32_bf16(pf[kk], vf[j][kk], oacc[j], 0, 0, 0);
    }
#pragma unroll
    for (int r = 0; r < 4; ++r)
#pragma unroll
        for (int m = 1; m < 16; m <<= 1) lrow[r] += __shfl_xor(lrow[r], m);
#pragma unroll
    for (int r = 0; r < 4; ++r) {
        float inv = 1.0f / lrow[r];
        int row = r0 + quad * 4 + r;
#pragma unroll
        for (int j = 0; j < 4; ++j)
            ob[(size_t)row * LHA + h * 64 + j * 16 + lr] = f2bf(oacc[j][r] * inv);
    }
}

// ---------------------------------------------------------------------------
extern "C" void kernel_launch(void* const* d_in, const int* in_sizes, int n_in,
                              void* d_out, int out_size, void* d_ws, size_t ws_size,
                              hipStream_t stream)
{
    const float* x    = (const float*)d_in[0];
    const float* nw1  = (const float*)d_in[1];
    const float* nw2  = (const float*)d_in[2];
    const float* cosT = (const float*)d_in[3];
    const float* sinT = (const float*)d_in[4];
    const int*   pos  = (const int*)d_in[5];
    const int   *qc = (const int*)d_in[6],  *kc = (const int*)d_in[10],
                *vc = (const int*)d_in[14], *oc = (const int*)d_in[18],
                *gc = (const int*)d_in[22], *uc = (const int*)d_in[26],
                *dc = (const int*)d_in[30];
    const float *qa = (const float*)d_in[7],  *ka = (const float*)d_in[11],
                *va = (const float*)d_in[15], *oa = (const float*)d_in[19],
                *ga = (const float*)d_in[23], *ua = (const float*)d_in[27],
                *da = (const float*)d_in[31];
    const float *qla = (const float*)d_in[8],  *kla = (const float*)d_in[12],
                *vla = (const float*)d_in[16], *ola = (const float*)d_in[20],
                *gla = (const float*)d_in[24], *ula = (const float*)d_in[28],
                *dla = (const float*)d_in[32];
    const float *qlb = (const float*)d_in[9],  *klb = (const float*)d_in[13],
                *vlb = (const float*)d_in[17], *olb = (const float*)d_in[21],
                *glb = (const float*)d_in[25], *ulb = (const float*)d_in[29],
                *dlb = (const float*)d_in[33];

    // workspace (peak ~58.1 MB; x1 overlays qbf+kpk which die after attn)
    char* ws = (char*)d_ws;
    unsigned short* h    = (unsigned short*)(ws + 0);          // [2048,1088]
    unsigned short* W    = (unsigned short*)(ws + 4456448);    // <= 11.9 MB
    unsigned short* qkv  = (unsigned short*)(ws + 16351232);   // [2048,3072]
    unsigned short* qbf  = (unsigned short*)(ws + 28934144);   // [2048,1024]
    unsigned short* kpk  = (unsigned short*)(ws + 33128448);   // 4 MB
    unsigned short* vpk  = (unsigned short*)(ws + 37322752);   // 4 MB
    unsigned short* obf  = (unsigned short*)(ws + 41517056);   // [2048,1088]
    float*          x1   = (float*)(ws + 28934144);            // overlays qbf+kpk
    unsigned short* hb   = (unsigned short*)(ws + 45973504);   // [2048,2880]
    unsigned short* lapk = (unsigned short*)(ws + 57769984);   // 280 x 1KB
    float* outp = (float*)d_out;

    // ---- attention block ----
    lora_prep<<<70, 256, 0, stream>>>(qla, kla, vla, ola, gla, ula, dla, lapk);
    rmsnorm_ext<<<Sq, 256, 0, stream>>>(x, nw1, h, LHA);
    lora_mfma<3><<<128, 256, 0, stream>>>(h, LHA, Dm, lapk, 0, 32, 64, 1024, 0, 0);
    dequant_qkv<<<1680, 256, 0, stream>>>(qc, kc, vc, qa, ka, va, qlb, klb, vlb, W);
    gemm128<<<dim3(NQKV / 128, Sq / 128), 256, 0, stream>>>(h, LHA, W, LWQ, KQ, qkv, NQKV);
    rope_pack<<<8704, 256, 0, stream>>>(qkv, cosT, sinT, pos, qbf, kpk, vpk);
    attn<<<512, 256, 0, stream>>>(qbf, kpk, vpk, obf);
    lora_mfma<1><<<128, 256, 0, stream>>>(obf, LHA, Dm, lapk, 96, 0, 0, 1024, 1040, 48);
    dequant_ext<<<560, 256, 0, stream>>>(oc, oa, olb, W, Dm, Dm, LWQ, 1024);
    gemm_s<0><<<dim3(Dm / 64, Sq / 64), 256, 0, stream>>>(obf, LHA, W, LWQ, KQ, x1, Dm, x);
    // ---- MLP block ----
    rmsnorm_ext<<<Sq, 256, 0, stream>>>(x1, nw2, h, LHA);
    lora_mfma<2><<<128, 256, 0, stream>>>(h, LHA, Dm, lapk, 128, 160, 0, 1024, 0, 0);
    dequant_gu<<<2904, 256, 0, stream>>>(gc, uc, ga, ua, glb, ulb, W);
    gemm_gu<<<dim3(NGU / 128, Sq / 128), 256, 0, stream>>>(h, LHA, W, LGU, LGU, hb);
    lora_mfma<1><<<128, 256, 0, stream>>>(hb, LHB, Fm, lapk, 192, 0, 0, 2816, 2832, 48);
    dequant_ext<<<1456, 256, 0, stream>>>(dc, da, dlb, W, Dm, Fm, LWD, 2816);
    gemm_s<1><<<dim3(Dm / 64, Sq / 64), 256, 0, stream>>>(hb, LHB, W, LWD, KD, outp, Dm, x1);
}

// Round 16
// 346.910 us; speedup vs baseline: 1.0344x; 1.0344x over previous
//
#include <hip/hip_runtime.h>
#include <stdint.h>

// ---------------------------------------------------------------------------
// MixedSparseSingleLayerWithGate: NF4-dequant QLoRA transformer layer, MI355X.
// R16 = R13 (best-known, 346.8us) + ONE change: gemm_gu B-side stride 1056
// (odd x64B de-alias; this exact A=1088/B=1056 config measured 43.5us twice).
// All other kernels/strides/workspace identical to R13.
// ---------------------------------------------------------------------------

#define Sq   2048
#define Dm   1024
#define Fm   2816
#define Hh   16
#define KE1  1088   // h & W_qkv stride / qkv & o reduction
#define KE2  1088   // obf & W_o stride
#define LGU  1056   // gate/up W stride and reduction (2112B = 33x64, odd)
#define KE3  2880   // hb & W_down stride / down reduction
#define NQKV 3072
#define NGU  5632

typedef short bf16x8 __attribute__((ext_vector_type(8)));
typedef float f32x4  __attribute__((ext_vector_type(4)));

__constant__ float NF4_LUT[16] = {
    -1.0f, -0.6961928009986877f, -0.5250730514526367f, -0.39491748809814453f,
    -0.28444138169288635f, -0.18477343022823334f, -0.09105003625154495f, 0.0f,
    0.07958029955625534f, 0.16093020141124725f, 0.24611230194568634f,
    0.33791524171829224f, 0.44070982933044434f, 0.5626170039176941f,
    0.7229568362236023f, 1.0f};

__device__ inline unsigned short f2bf(float f) {
    union { float f; uint32_t u; } v; v.f = f;
    uint32_t u = v.u;
    return (unsigned short)((u + 0x7FFFu + ((u >> 16) & 1u)) >> 16);
}
__device__ inline float bf2f(unsigned short h) {
    union { uint32_t u; float f; } v; v.u = ((uint32_t)h) << 16;
    return v.f;
}
__device__ inline unsigned short truncbf(float f) {
    union { float f; uint32_t u; } v; v.f = f;
    return (unsigned short)(v.u >> 16);
}

// async global->LDS, 16 B per lane; LDS dest = wave-uniform base + lane*16
#define GLD16(gp, lp)                                                         \
    __builtin_amdgcn_global_load_lds(                                         \
        (__attribute__((address_space(1))) void*)(uintptr_t)(gp),             \
        (__attribute__((address_space(3))) void*)(uint32_t)(uintptr_t)(lp),   \
        16, 0, 0)

// --------------------------- rmsnorm -> bf16 ext -----------------------------
__global__ __launch_bounds__(256) void rmsnorm_ext(
    const float* __restrict__ X, const float* __restrict__ W,
    unsigned short* Hout, int ldh)
{
    int s = blockIdx.x, tid = threadIdx.x;
    const float4 v = *(const float4*)(X + (size_t)s * Dm + tid * 4);
    float ss = v.x * v.x + v.y * v.y + v.z * v.z + v.w * v.w;
#pragma unroll
    for (int m = 1; m < 64; m <<= 1) ss += __shfl_xor(ss, m);
    __shared__ float red[4];
    int lane = tid & 63, wave = tid >> 6;
    if (lane == 0) red[wave] = ss;
    __syncthreads();
    float scale = rsqrtf((red[0] + red[1] + red[2] + red[3]) * (1.0f / Dm) + 1e-10f);
    const float4 w = *(const float4*)(W + tid * 4);
    alignas(8) unsigned short o[4];
    o[0] = f2bf(v.x * scale * w.x);
    o[1] = f2bf(v.y * scale * w.y);
    o[2] = f2bf(v.z * scale * w.z);
    o[3] = f2bf(v.w * scale * w.w);
    *(ushort4*)(Hout + (size_t)s * ldh + tid * 4) = *(ushort4*)o;
    if (tid < 64) Hout[(size_t)s * ldh + Dm + tid] = 0;   // zero 1024..1088
}

// -------- pack la matrices into MFMA B-fragment chunks (bf16) ---------------
__global__ __launch_bounds__(256) void lora_prep(
    const float* __restrict__ qla, const float* __restrict__ kla,
    const float* __restrict__ vla, const float* __restrict__ ola,
    const float* __restrict__ gla, const float* __restrict__ ula,
    const float* __restrict__ dla, unsigned short* __restrict__ lapk)
{
    int tid = threadIdx.x;
    int chunk = blockIdx.x * 4 + (tid >> 6);
    int lane = tid & 63;
    int lr = lane & 15, quad = lane >> 4;
    const float* la;
    int lc;
    if (chunk < 192) {
        int m = chunk >> 5; lc = chunk & 31;
        la = (m == 0) ? qla : (m == 1) ? kla : (m == 2) ? vla
           : (m == 3) ? ola : (m == 4) ? gla : ula;
    } else {
        la = dla; lc = chunk - 192;
    }
    alignas(16) unsigned short out[8];
#pragma unroll
    for (int e = 0; e < 8; ++e)
        out[e] = f2bf(la[(size_t)(lc * 32 + quad * 8 + e) * 16 + lr]);
    *(uint4*)(lapk + (size_t)chunk * 512 + lane * 8) = *(uint4*)out;
}

// -------- T = A @ la via MFMA; 16-row strips, 4-way wave K-split ------------
template<int NM>
__global__ __launch_bounds__(256) void lora_mfma(
    unsigned short* Aext, int lda, int K,
    const unsigned short* __restrict__ lapk, int c0, int c1, int c2,
    int toff, int zoff, int zn)
{
    int tid = threadIdx.x;
    int lane = tid & 63, wave = tid >> 6;
    int lr = lane & 15, quad = lane >> 4;
    int r0 = blockIdx.x * 16;
    int nc4 = K >> 7;                       // chunks per wave
    int gc0 = wave * nc4;
    const unsigned short* Ab = Aext + (size_t)(r0 + lr) * lda + quad * 8;
    int cb[3] = {c0, c1, c2};
    f32x4 zero = {0.f, 0.f, 0.f, 0.f};
    f32x4 acc[NM];
#pragma unroll
    for (int m = 0; m < NM; ++m) acc[m] = zero;
    for (int cc = 0; cc < nc4; ++cc) {
        int gc = gc0 + cc;
        bf16x8 af = *(const bf16x8*)(Ab + gc * 32);
#pragma unroll
        for (int m = 0; m < NM; ++m) {
            bf16x8 bf = *(const bf16x8*)(lapk + (size_t)(cb[m] + gc) * 512 + lane * 8);
            acc[m] = __builtin_amdgcn_mfma_f32_16x16x32_bf16(af, bf, acc[m], 0, 0, 0);
        }
    }
    __shared__ float red[3][NM * 64 * 4];
    if (wave > 0) {
#pragma unroll
        for (int m = 0; m < NM; ++m)
#pragma unroll
            for (int r = 0; r < 4; ++r)
                red[wave - 1][(m * 64 + lane) * 4 + r] = acc[m][r];
    }
    __syncthreads();
    if (wave == 0) {
#pragma unroll
        for (int m = 0; m < NM; ++m)
#pragma unroll
            for (int r = 0; r < 4; ++r)
                acc[m][r] += red[0][(m * 64 + lane) * 4 + r]
                           + red[1][(m * 64 + lane) * 4 + r]
                           + red[2][(m * 64 + lane) * 4 + r];
#pragma unroll
        for (int r = 0; r < 4; ++r) {
            int row = r0 + quad * 4 + r;
#pragma unroll
            for (int m = 0; m < NM; ++m)
                Aext[(size_t)row * lda + toff + m * 16 + lr] = f2bf(acc[m][r]);
        }
        if (zn > 0) {
            int row = r0 + lr, j0 = quad * 4;
            for (int j = j0; j < zn; j += 64) {
                alignas(8) unsigned short z4[4] = {0, 0, 0, 0};
                *(ushort4*)(Aext + (size_t)row * lda + zoff + j) = *(ushort4*)z4;
            }
        }
    }
}

// ---------------- NF4 dequant helpers (bf16, K-extended rows) ---------------
__device__ inline void dq_row8(const float* lut, const int* cod, const float* am,
                               const float* lb, int nr, int c8, int K, int Nlb,
                               int toff, unsigned short* out)
{
    if (c8 < K) {
        size_t base = (size_t)nr * K + c8;
        const int4* cp = (const int4*)(cod + base);
        int4 ca = cp[0], cb = cp[1];
        float a = am[base >> 6];
        out[0] = f2bf(lut[ca.x] * a); out[1] = f2bf(lut[ca.y] * a);
        out[2] = f2bf(lut[ca.z] * a); out[3] = f2bf(lut[ca.w] * a);
        out[4] = f2bf(lut[cb.x] * a); out[5] = f2bf(lut[cb.y] * a);
        out[6] = f2bf(lut[cb.z] * a); out[7] = f2bf(lut[cb.w] * a);
    } else {
        int r = c8 - toff;
#pragma unroll
        for (int i = 0; i < 8; ++i) out[i] = 0;
        if (r >= 0 && r < 16) {
#pragma unroll
            for (int i = 0; i < 8; ++i) out[i] = f2bf(lb[(size_t)(r + i) * Nlb + nr]);
        }
    }
}

// q/k/v fused: W rows [0,1024)=q, [1024,2048)=k, [2048,3072)=v ; ldw=KE1
__global__ __launch_bounds__(256) void dequant_qkv(
    const int* __restrict__ qc, const int* __restrict__ kc, const int* __restrict__ vc,
    const float* __restrict__ qa, const float* __restrict__ ka, const float* __restrict__ va,
    const float* __restrict__ qlb, const float* __restrict__ klb, const float* __restrict__ vlb,
    unsigned short* __restrict__ Wout)
{
    __shared__ float lut[16];
    if (threadIdx.x < 16) lut[threadIdx.x] = NF4_LUT[threadIdx.x];
    __syncthreads();
    int idx = blockIdx.x * 256 + threadIdx.x;        // 3072*136
    int n = idx / 136;
    int c8 = (idx - n * 136) * 8;
    int seg = n >> 10, nr = n & 1023;
    const int* cod   = (seg == 0) ? qc : (seg == 1) ? kc : vc;
    const float* am  = (seg == 0) ? qa : (seg == 1) ? ka : va;
    const float* lb  = (seg == 0) ? qlb : (seg == 1) ? klb : vlb;
    int toff = 1024 + (seg << 4);
    alignas(16) unsigned short out[8];
    dq_row8(lut, cod, am, lb, nr, c8, 1024, 1024, toff, out);
    *(uint4*)(Wout + (size_t)n * KE1 + c8) = *(uint4*)out;
}

// gate/up fused + interleaved: W row 2m = gate m (toff 1024), 2m+1 = up m (1040)
// stride LGU = 1056 (132 chunks) — the single R16 change vs R13.
__global__ __launch_bounds__(256) void dequant_gu(
    const int* __restrict__ gc, const int* __restrict__ uc,
    const float* __restrict__ ga, const float* __restrict__ ua,
    const float* __restrict__ glb, const float* __restrict__ ulb,
    unsigned short* __restrict__ Wout)
{
    __shared__ float lut[16];
    if (threadIdx.x < 16) lut[threadIdx.x] = NF4_LUT[threadIdx.x];
    __syncthreads();
    int idx = blockIdx.x * 256 + threadIdx.x;        // 5632*132
    int n = idx / 132;
    int c8 = (idx - n * 132) * 8;
    int m = n >> 1, mat = n & 1;
    const int* cod  = mat ? uc : gc;
    const float* am = mat ? ua : ga;
    const float* lb = mat ? ulb : glb;
    int toff = 1024 + (mat << 4);
    alignas(16) unsigned short out[8];
    dq_row8(lut, cod, am, lb, m, c8, 1024, Fm, toff, out);
    *(uint4*)(Wout + (size_t)n * LGU + c8) = *(uint4*)out;
}

// generic (o-proj, down)
__global__ __launch_bounds__(256) void dequant_ext(
    const int* __restrict__ codes, const float* __restrict__ absmax,
    const float* __restrict__ lb, unsigned short* __restrict__ Wout,
    int Nproj, int K, int ldw, int toff)
{
    __shared__ float lut[16];
    if (threadIdx.x < 16) lut[threadIdx.x] = NF4_LUT[threadIdx.x];
    __syncthreads();
    int idx = blockIdx.x * 256 + threadIdx.x;
    int cpr = ldw >> 3;
    int n = idx / cpr;
    if (n >= Nproj) return;
    int c8 = (idx - n * cpr) * 8;
    alignas(16) unsigned short out[8];
    dq_row8(lut, codes, absmax, lb, n, c8, K, Nproj, toff, out);
    *(uint4*)(Wout + (size_t)n * ldw + c8) = *(uint4*)out;
}

// ------------------- GEMM 128x128, dbuf, bf16-out (qkv) ---------------------
// grid (N/128, Sq/128) col-fast; swizzled LDS (0 conflicts).
__global__ __launch_bounds__(256) void gemm128(
    const unsigned short* __restrict__ A, int lda,
    const unsigned short* __restrict__ B, int ldb, int K,
    unsigned short* __restrict__ Cb, int ldc)
{
    __shared__ __align__(16) unsigned short At[2][128 * 32];
    __shared__ __align__(16) unsigned short Bt[2][128 * 32];
    int tid = threadIdx.x;
    int lane = tid & 63, wave = tid >> 6;
    int lr = lane & 15, quad = lane >> 4;
    int wm = (wave >> 1) * 64, wn = (wave & 1) * 64;
    int row0 = blockIdx.y * 128, col0 = blockIdx.x * 128;
    f32x4 acc[4][4];
    f32x4 zero = {0.f, 0.f, 0.f, 0.f};
#pragma unroll
    for (int i = 0; i < 4; ++i)
#pragma unroll
        for (int j = 0; j < 4; ++j) acc[i][j] = zero;
    int sw = ((tid & 3) ^ ((tid >> 3) & 3)) * 8;
    const unsigned short* Ag  = A + (size_t)(row0 + (tid >> 2)) * lda + sw;
    const unsigned short* Ag2 = Ag + (size_t)64 * lda;
    const unsigned short* Bg  = B + (size_t)(col0 + (tid >> 2)) * ldb + sw;
    const unsigned short* Bg2 = Bg + (size_t)64 * ldb;
    int l0 = tid * 8, l1 = (tid + 256) * 8;
    GLD16(Ag, At[0] + l0); GLD16(Ag2, At[0] + l1);
    GLD16(Bg, Bt[0] + l0); GLD16(Bg2, Bt[0] + l1);
    int sq = (quad ^ ((lr >> 1) & 3)) * 8;
    int nIter = K >> 5;
    for (int it = 0; it < nIter; ++it) {
        int cur = it & 1;
        __syncthreads();
        if (it + 1 < nIter) {
            int k = (it + 1) << 5, nx = cur ^ 1;
            GLD16(Ag + k, At[nx] + l0); GLD16(Ag2 + k, At[nx] + l1);
            GLD16(Bg + k, Bt[nx] + l0); GLD16(Bg2 + k, Bt[nx] + l1);
        }
        bf16x8 af[4], bfr[4];
#pragma unroll
        for (int i = 0; i < 4; ++i)
            af[i] = *(const bf16x8*)(At[cur] + (wm + i * 16 + lr) * 32 + sq);
#pragma unroll
        for (int j = 0; j < 4; ++j)
            bfr[j] = *(const bf16x8*)(Bt[cur] + (wn + j * 16 + lr) * 32 + sq);
#pragma unroll
        for (int i = 0; i < 4; ++i)
#pragma unroll
            for (int j = 0; j < 4; ++j)
                acc[i][j] = __builtin_amdgcn_mfma_f32_16x16x32_bf16(af[i], bfr[j], acc[i][j], 0, 0, 0);
    }
#pragma unroll
    for (int i = 0; i < 4; ++i) {
        int rowb = row0 + wm + i * 16 + quad * 4;
#pragma unroll
        for (int j = 0; j < 4; ++j) {
            int col = col0 + wn + j * 16 + lr;
#pragma unroll
            for (int r = 0; r < 4; ++r)
                Cb[(size_t)(rowb + r) * ldc + col] = f2bf(acc[i][j][r]);
        }
    }
}

// ---------------- GEMM 128x128, dbuf, SwiGLU epilogue (gate/up) -------------
__global__ __launch_bounds__(256) void gemm_gu(
    const unsigned short* __restrict__ A, int lda,
    const unsigned short* __restrict__ B, int ldb, int K,
    unsigned short* __restrict__ Hb)
{
    __shared__ __align__(16) unsigned short At[2][128 * 32];
    __shared__ __align__(16) unsigned short Bt[2][128 * 32];
    int tid = threadIdx.x;
    int lane = tid & 63, wave = tid >> 6;
    int lr = lane & 15, quad = lane >> 4;
    int wm = (wave >> 1) * 64, wn = (wave & 1) * 64;
    int row0 = blockIdx.y * 128, col0 = blockIdx.x * 128;
    f32x4 acc[4][4];
    f32x4 zero = {0.f, 0.f, 0.f, 0.f};
#pragma unroll
    for (int i = 0; i < 4; ++i)
#pragma unroll
        for (int j = 0; j < 4; ++j) acc[i][j] = zero;
    int sw = ((tid & 3) ^ ((tid >> 3) & 3)) * 8;
    const unsigned short* Ag  = A + (size_t)(row0 + (tid >> 2)) * lda + sw;
    const unsigned short* Ag2 = Ag + (size_t)64 * lda;
    const unsigned short* Bg  = B + (size_t)(col0 + (tid >> 2)) * ldb + sw;
    const unsigned short* Bg2 = Bg + (size_t)64 * ldb;
    int l0 = tid * 8, l1 = (tid + 256) * 8;
    GLD16(Ag, At[0] + l0); GLD16(Ag2, At[0] + l1);
    GLD16(Bg, Bt[0] + l0); GLD16(Bg2, Bt[0] + l1);
    int sq = (quad ^ ((lr >> 1) & 3)) * 8;
    int nIter = K >> 5;
    for (int it = 0; it < nIter; ++it) {
        int cur = it & 1;
        __syncthreads();
        if (it + 1 < nIter) {
            int k = (it + 1) << 5, nx = cur ^ 1;
            GLD16(Ag + k, At[nx] + l0); GLD16(Ag2 + k, At[nx] + l1);
            GLD16(Bg + k, Bt[nx] + l0); GLD16(Bg2 + k, Bt[nx] + l1);
        }
        bf16x8 af[4], bfr[4];
#pragma unroll
        for (int i = 0; i < 4; ++i)
            af[i] = *(const bf16x8*)(At[cur] + (wm + i * 16 + lr) * 32 + sq);
#pragma unroll
        for (int j = 0; j < 4; ++j)
            bfr[j] = *(const bf16x8*)(Bt[cur] + (wn + j * 16 + lr) * 32 + sq);
#pragma unroll
        for (int i = 0; i < 4; ++i)
#pragma unroll
            for (int j = 0; j < 4; ++j)
                acc[i][j] = __builtin_amdgcn_mfma_f32_16x16x32_bf16(af[i], bfr[j], acc[i][j], 0, 0, 0);
    }
#pragma unroll
    for (int i = 0; i < 4; ++i) {
        int rowb = row0 + wm + i * 16 + quad * 4;
#pragma unroll
        for (int j = 0; j < 4; ++j) {
            int col = col0 + wn + j * 16 + lr;     // even=gate, odd=up
#pragma unroll
            for (int r = 0; r < 4; ++r) {
                float own = acc[i][j][r];
                float oth = __shfl_xor(own, 1);
                if (!(lr & 1)) {
                    float sig = 1.0f / (1.0f + __expf(-own));
                    Hb[(size_t)(rowb + r) * KE3 + (col >> 1)] = f2bf(oth * own * sig);
                }
            }
        }
    }
}

// ------ GEMM 64x64, BK=64 dbuf, f32 + residual out (o, down) ----------------
template<int TAG>
__global__ __launch_bounds__(256) void gemm_s(
    const unsigned short* __restrict__ A, int lda,
    const unsigned short* __restrict__ B, int ldb, int K,
    float* __restrict__ Cf, int ldc, const float* __restrict__ Radd)
{
    __shared__ __align__(16) unsigned short At[2][64 * 64];
    __shared__ __align__(16) unsigned short Bt[2][64 * 64];
    int tid = threadIdx.x;
    int lane = tid & 63, wave = tid >> 6;
    int lr = lane & 15, quad = lane >> 4;
    int row0 = blockIdx.y * 64, col0 = blockIdx.x * 64;
    f32x4 acc[4];
    f32x4 zero = {0.f, 0.f, 0.f, 0.f};
#pragma unroll
    for (int j = 0; j < 4; ++j) acc[j] = zero;
    int rs = tid >> 3;
    int g8 = ((tid & 7) ^ (rs & 7)) * 8;
    const unsigned short* Ag  = A + (size_t)(row0 + rs) * lda + g8;
    const unsigned short* Ag2 = Ag + (size_t)32 * lda;
    const unsigned short* Bg  = B + (size_t)(col0 + rs) * ldb + g8;
    const unsigned short* Bg2 = Bg + (size_t)32 * ldb;
    int l0 = tid * 8, l1 = (tid + 256) * 8;
    GLD16(Ag, At[0] + l0); GLD16(Ag2, At[0] + l1);
    GLD16(Bg, Bt[0] + l0); GLD16(Bg2, Bt[0] + l1);
    int c0 = (quad ^ (lr & 7)) * 8;
    int c1 = ((4 + quad) ^ (lr & 7)) * 8;
    int nIter = K >> 6;
    for (int it = 0; it < nIter; ++it) {
        int cur = it & 1;
        __syncthreads();
        if (it + 1 < nIter) {
            int k = (it + 1) << 6, nx = cur ^ 1;
            GLD16(Ag + k, At[nx] + l0); GLD16(Ag2 + k, At[nx] + l1);
            GLD16(Bg + k, Bt[nx] + l0); GLD16(Bg2 + k, Bt[nx] + l1);
        }
        const unsigned short* arow = At[cur] + (wave * 16 + lr) * 64;
        bf16x8 a0 = *(const bf16x8*)(arow + c0);
        bf16x8 a1 = *(const bf16x8*)(arow + c1);
        bf16x8 b0[4], b1[4];
#pragma unroll
        for (int j = 0; j < 4; ++j) {
            const unsigned short* brow = Bt[cur] + (j * 16 + lr) * 64;
            b0[j] = *(const bf16x8*)(brow + c0);
            b1[j] = *(const bf16x8*)(brow + c1);
        }
#pragma unroll
        for (int j = 0; j < 4; ++j) {
            acc[j] = __builtin_amdgcn_mfma_f32_16x16x32_bf16(a0, b0[j], acc[j], 0, 0, 0);
            acc[j] = __builtin_amdgcn_mfma_f32_16x16x32_bf16(a1, b1[j], acc[j], 0, 0, 0);
        }
    }
    int rowb = row0 + wave * 16 + quad * 4;
#pragma unroll
    for (int j = 0; j < 4; ++j) {
        int col = col0 + j * 16 + lr;
#pragma unroll
        for (int r = 0; r < 4; ++r) {
            size_t o = (size_t)(rowb + r) * ldc + col;
            Cf[o] = acc[j][r] + Radd[o];
        }
    }
}

// -------- fused rope(q) + rope+fragment-pack(K) + fragment-pack(V) ----------
__global__ __launch_bounds__(256) void rope_pack(
    const unsigned short* __restrict__ qkv,
    const float* __restrict__ cosT, const float* __restrict__ sinT,
    const int* __restrict__ pos,
    unsigned short* __restrict__ qb, unsigned short* __restrict__ kpk,
    unsigned short* __restrict__ vpk)
{
    int b = blockIdx.x, tid = threadIdx.x;
    if (b < 8192) {                              // Q rope (coalesced write)
        int idx = b * 256 + tid;                 // over 2048*1024
        int s = idx >> 10, col = idx & 1023, d = col & 63;
        int p = pos[s];
        float c = cosT[p * 64 + d], sn = sinT[p * 64 + d];
        int partner = (d < 32) ? (col + 32) : (col - 32);
        float sgn = (d < 32) ? -1.f : 1.f;
        const unsigned short* row = qkv + (size_t)s * NQKV;
        float q = bf2f(row[col]), q2 = bf2f(row[partner]);
        qb[idx] = f2bf((q * c + sgn * q2 * sn) * 0.125f);
    } else if (b < 9216) {                       // K rope + pack, 16B/thread
        int g = (b - 8192) * 256 + tid;          // 0..262143
        int lr = g & 15, quad = (g >> 4) & 3, cch = (g >> 6) & 1;
        int t = (g >> 7) & 127, h = g >> 14;
        int s = t * 16 + lr;
        int p = pos[s];
        int d0 = cch * 32 + quad * 8;
        const unsigned short* krow = qkv + (size_t)s * NQKV + Dm + h * 64;
        uint4 kv8 = *(const uint4*)(krow + d0);
        uint4 kp8 = *(const uint4*)(krow + ((d0 + 32) & 63));
        float sgn = (d0 < 32) ? -1.f : 1.f;
        const float* cp = cosT + p * 64 + d0;
        const float* sp = sinT + p * 64 + d0;
        const unsigned short* ke = (const unsigned short*)&kv8;
        const unsigned short* pe = (const unsigned short*)&kp8;
        alignas(16) unsigned short out[8];
#pragma unroll
        for (int e = 0; e < 8; ++e)
            out[e] = f2bf(bf2f(ke[e]) * cp[e] + sgn * bf2f(pe[e]) * sp[e]);
        *(uint4*)(kpk + (size_t)g * 8) = *(uint4*)out;
    } else {                                     // V pack, 16B/thread
        int g = (b - 9216) * 256 + tid;          // 0..262143
        int lrr = g & 15, quad = (g >> 4) & 3, kk = (g >> 6) & 3;
        int j = (g >> 8) & 3, kt = (g >> 10) & 15, h = g >> 14;
        int d = j * 16 + lrr;
        int sbase = kt * 128 + kk * 32 + quad * 8;
        alignas(16) unsigned short out[8];
#pragma unroll
        for (int e = 0; e < 8; ++e)
            out[e] = qkv[(size_t)(sbase + e) * NQKV + 2048 + h * 64 + d];
        *(uint4*)(vpk + (size_t)g * 8) = *(uint4*)out;
    }
}

// ------------- flash attention: packed frags, no-max softmax ----------------
__global__ __launch_bounds__(256) void attn(
    const unsigned short* __restrict__ qb, const unsigned short* __restrict__ kpk,
    const unsigned short* __restrict__ vpk, unsigned short* __restrict__ ob)
{
    __shared__ __align__(16) unsigned short Ps[4][16 * 136];
    int tid = threadIdx.x;
    int lane = tid & 63, wave = tid >> 6;
    int lr = lane & 15, quad = lane >> 4;
    int idx = blockIdx.x;
    int t_ = idx >> 4;
    int qt = (idx < 256) ? (31 - t_) : (t_ - 16);
    int h = idx & 15;
    int r0 = qt * 64 + wave * 16;
    const unsigned short* qp = qb + (size_t)(r0 + lr) * Dm + h * 64 + quad * 8;
    bf16x8 qf0 = *(const bf16x8*)qp;
    bf16x8 qf1 = *(const bf16x8*)(qp + 32);
    const unsigned short* kpb = kpk + (size_t)h * 128 * 1024 + lane * 8;
    const unsigned short* vpb = vpk + (size_t)h * 16 * 16 * 512 + lane * 8;
    f32x4 zero = {0.f, 0.f, 0.f, 0.f};
    f32x4 oacc[4];
#pragma unroll
    for (int j = 0; j < 4; ++j) oacc[j] = zero;
    float lrow[4] = {0.f, 0.f, 0.f, 0.f};
    int ntile = (qt * 64 + 191) >> 7;

    for (int kt = 0; kt < ntile; ++kt) {
        int k0 = kt << 7;
        f32x4 sf[8];
#pragma unroll
        for (int jj = 0; jj < 8; ++jj) {
            const unsigned short* kp = kpb + (size_t)(kt * 8 + jj) * 1024;
            bf16x8 kf0 = *(const bf16x8*)kp;
            bf16x8 kf1 = *(const bf16x8*)(kp + 512);
            f32x4 z = zero;
            z = __builtin_amdgcn_mfma_f32_16x16x32_bf16(qf0, kf0, z, 0, 0, 0);
            z = __builtin_amdgcn_mfma_f32_16x16x32_bf16(qf1, kf1, z, 0, 0, 0);
            sf[jj] = z;
        }
        bf16x8 vf[4][4];
#pragma unroll
        for (int j = 0; j < 4; ++j)
#pragma unroll
            for (int kk = 0; kk < 4; ++kk)
                vf[j][kk] = *(const bf16x8*)(vpb + (size_t)((kt * 4 + j) * 4 + kk) * 512);
        if (kt == ntile - 1) {
#pragma unroll
            for (int jj = 0; jj < 8; ++jj)
#pragma unroll
                for (int r = 0; r < 4; ++r)
                    if (k0 + jj * 16 + lr > r0 + quad * 4 + r)
                        sf[jj][r] = -1e30f;
        }
#pragma unroll
        for (int jj = 0; jj < 8; ++jj)
#pragma unroll
            for (int r = 0; r < 4; ++r) {
                float p = __expf(sf[jj][r]);
                sf[jj][r] = p;
                lrow[r] += p;
            }
#pragma unroll
        for (int jj = 0; jj < 8; ++jj)
#pragma unroll
            for (int r = 0; r < 4; ++r)
                Ps[wave][(quad * 4 + r) * 136 + jj * 16 + lr] = truncbf(sf[jj][r]);
        bf16x8 pf[4];
#pragma unroll
        for (int kk = 0; kk < 4; ++kk)
            pf[kk] = *(const bf16x8*)(&Ps[wave][lr * 136 + kk * 32 + quad * 8]);
#pragma unroll
        for (int j = 0; j < 4; ++j)
#pragma unroll
            for (int kk = 0; kk < 4; ++kk)
                oacc[j] = __builtin_amdgcn_mfma_f32_16x16x32_bf16(pf[kk], vf[j][kk], oacc[j], 0, 0, 0);
    }
#pragma unroll
    for (int r = 0; r < 4; ++r)
#pragma unroll
        for (int m = 1; m < 16; m <<= 1) lrow[r] += __shfl_xor(lrow[r], m);
#pragma unroll
    for (int r = 0; r < 4; ++r) {
        float inv = 1.0f / lrow[r];
        int row = r0 + quad * 4 + r;
#pragma unroll
        for (int j = 0; j < 4; ++j)
            ob[(size_t)row * KE2 + h * 64 + j * 16 + lr] = f2bf(oacc[j][r] * inv);
    }
}

// ---------------------------------------------------------------------------
extern "C" void kernel_launch(void* const* d_in, const int* in_sizes, int n_in,
                              void* d_out, int out_size, void* d_ws, size_t ws_size,
                              hipStream_t stream)
{
    const float* x    = (const float*)d_in[0];
    const float* nw1  = (const float*)d_in[1];
    const float* nw2  = (const float*)d_in[2];
    const float* cosT = (const float*)d_in[3];
    const float* sinT = (const float*)d_in[4];
    const int*   pos  = (const int*)d_in[5];
    const int   *qc = (const int*)d_in[6],  *kc = (const int*)d_in[10],
                *vc = (const int*)d_in[14], *oc = (const int*)d_in[18],
                *gc = (const int*)d_in[22], *uc = (const int*)d_in[26],
                *dc = (const int*)d_in[30];
    const float *qa = (const float*)d_in[7],  *ka = (const float*)d_in[11],
                *va = (const float*)d_in[15], *oa = (const float*)d_in[19],
                *ga = (const float*)d_in[23], *ua = (const float*)d_in[27],
                *da = (const float*)d_in[31];
    const float *qla = (const float*)d_in[8],  *kla = (const float*)d_in[12],
                *vla = (const float*)d_in[16], *ola = (const float*)d_in[20],
                *gla = (const float*)d_in[24], *ula = (const float*)d_in[28],
                *dla = (const float*)d_in[32];
    const float *qlb = (const float*)d_in[9],  *klb = (const float*)d_in[13],
                *vlb = (const float*)d_in[17], *olb = (const float*)d_in[21],
                *glb = (const float*)d_in[25], *ulb = (const float*)d_in[29],
                *dlb = (const float*)d_in[33];

    // workspace (peak ~58.4 MB; x1 overlays qbf+kpk which die after attn)
    char* ws = (char*)d_ws;
    unsigned short* h    = (unsigned short*)(ws + 0);          // [2048,1088]
    unsigned short* W    = (unsigned short*)(ws + 4456448);    // <= [5632,1088]
    unsigned short* qkv  = (unsigned short*)(ws + 16711680);   // [2048,3072]
    unsigned short* qbf  = (unsigned short*)(ws + 29294592);   // [2048,1024]
    unsigned short* kpk  = (unsigned short*)(ws + 33488896);   // 4 MB
    unsigned short* vpk  = (unsigned short*)(ws + 37683200);   // 4 MB
    unsigned short* obf  = (unsigned short*)(ws + 41877504);   // [2048,1088]
    float*          x1   = (float*)(ws + 29294592);            // overlays qbf+kpk
    unsigned short* hb   = (unsigned short*)(ws + 46333952);   // [2048,2880]
    unsigned short* lapk = (unsigned short*)(ws + 58130432);   // 280 x 1KB
    float* outp = (float*)d_out;

    // ---- attention block ----
    lora_prep<<<70, 256, 0, stream>>>(qla, kla, vla, ola, gla, ula, dla, lapk);
    rmsnorm_ext<<<Sq, 256, 0, stream>>>(x, nw1, h, KE1);
    lora_mfma<3><<<128, 256, 0, stream>>>(h, KE1, Dm, lapk, 0, 32, 64, 1024, 0, 0);
    dequant_qkv<<<1632, 256, 0, stream>>>(qc, kc, vc, qa, ka, va, qlb, klb, vlb, W);
    gemm128<<<dim3(NQKV / 128, Sq / 128), 256, 0, stream>>>(h, KE1, W, KE1, KE1, qkv, NQKV);
    rope_pack<<<10240, 256, 0, stream>>>(qkv, cosT, sinT, pos, qbf, kpk, vpk);
    attn<<<512, 256, 0, stream>>>(qbf, kpk, vpk, obf);
    lora_mfma<1><<<128, 256, 0, stream>>>(obf, KE2, Dm, lapk, 96, 0, 0, 1024, 1040, 16);
    dequant_ext<<<544, 256, 0, stream>>>(oc, oa, olb, W, Dm, Dm, KE2, 1024);
    gemm_s<0><<<dim3(Dm / 64, Sq / 64), 256, 0, stream>>>(obf, KE2, W, KE2, KE2, x1, Dm, x);
    // ---- MLP block ----
    rmsnorm_ext<<<Sq, 256, 0, stream>>>(x1, nw2, h, KE1);
    lora_mfma<2><<<128, 256, 0, stream>>>(h, KE1, Dm, lapk, 128, 160, 0, 1024, 0, 0);
    dequant_gu<<<2904, 256, 0, stream>>>(gc, uc, ga, ua, glb, ulb, W);
    gemm_gu<<<dim3(NGU / 128, Sq / 128), 256, 0, stream>>>(h, KE1, W, LGU, LGU, hb);
    lora_mfma<1><<<128, 256, 0, stream>>>(hb, KE3, Fm, lapk, 192, 0, 0, 2816, 2832, 16);
    dequant_ext<<<1440, 256, 0, stream>>>(dc, da, dlb, W, Dm, Fm, KE3, 2816);
    gemm_s<1><<<dim3(Dm / 64, Sq / 64), 256, 0, stream>>>(hb, KE3, W, KE3, KE3, outp, Dm, x1);
}

// Round 17
// 345.084 us; speedup vs baseline: 1.0399x; 1.0053x over previous
//
#include <hip/hip_runtime.h>
#include <stdint.h>

// ---------------------------------------------------------------------------
// MixedSparseSingleLayerWithGate: NF4-dequant QLoRA transformer layer, MI355X.
// R17 = R16 + rotated W_gu layout: stride 1088 (x128B-aligned row starts ->
// fast dequant writes) with per-row 64B-chunk rotation phys=(virt+row)%34
// (read-side channel de-alias, replacing the odd-stride trick). gemm_gu
// staging tracks the rotation with a wrapping counter. Everything else = R16.
// ---------------------------------------------------------------------------

#define Sq   2048
#define Dm   1024
#define Fm   2816
#define Hh   16
#define KE1  1088   // h & W_qkv stride / qkv & o reduction
#define KE2  1088   // obf & W_o stride
#define LGW  1088   // gate/up W stride (rotated rows), reduction K = 1088
#define KE3  2880   // hb & W_down stride / down reduction
#define NQKV 3072
#define NGU  5632

typedef short bf16x8 __attribute__((ext_vector_type(8)));
typedef float f32x4  __attribute__((ext_vector_type(4)));

__constant__ float NF4_LUT[16] = {
    -1.0f, -0.6961928009986877f, -0.5250730514526367f, -0.39491748809814453f,
    -0.28444138169288635f, -0.18477343022823334f, -0.09105003625154495f, 0.0f,
    0.07958029955625534f, 0.16093020141124725f, 0.24611230194568634f,
    0.33791524171829224f, 0.44070982933044434f, 0.5626170039176941f,
    0.7229568362236023f, 1.0f};

__device__ inline unsigned short f2bf(float f) {
    union { float f; uint32_t u; } v; v.f = f;
    uint32_t u = v.u;
    return (unsigned short)((u + 0x7FFFu + ((u >> 16) & 1u)) >> 16);
}
__device__ inline float bf2f(unsigned short h) {
    union { uint32_t u; float f; } v; v.u = ((uint32_t)h) << 16;
    return v.f;
}
__device__ inline unsigned short truncbf(float f) {
    union { float f; uint32_t u; } v; v.f = f;
    return (unsigned short)(v.u >> 16);
}

// async global->LDS, 16 B per lane; LDS dest = wave-uniform base + lane*16
#define GLD16(gp, lp)                                                         \
    __builtin_amdgcn_global_load_lds(                                         \
        (__attribute__((address_space(1))) void*)(uintptr_t)(gp),             \
        (__attribute__((address_space(3))) void*)(uint32_t)(uintptr_t)(lp),   \
        16, 0, 0)

// --------------------------- rmsnorm -> bf16 ext -----------------------------
__global__ __launch_bounds__(256) void rmsnorm_ext(
    const float* __restrict__ X, const float* __restrict__ W,
    unsigned short* Hout, int ldh)
{
    int s = blockIdx.x, tid = threadIdx.x;
    const float4 v = *(const float4*)(X + (size_t)s * Dm + tid * 4);
    float ss = v.x * v.x + v.y * v.y + v.z * v.z + v.w * v.w;
#pragma unroll
    for (int m = 1; m < 64; m <<= 1) ss += __shfl_xor(ss, m);
    __shared__ float red[4];
    int lane = tid & 63, wave = tid >> 6;
    if (lane == 0) red[wave] = ss;
    __syncthreads();
    float scale = rsqrtf((red[0] + red[1] + red[2] + red[3]) * (1.0f / Dm) + 1e-10f);
    const float4 w = *(const float4*)(W + tid * 4);
    alignas(8) unsigned short o[4];
    o[0] = f2bf(v.x * scale * w.x);
    o[1] = f2bf(v.y * scale * w.y);
    o[2] = f2bf(v.z * scale * w.z);
    o[3] = f2bf(v.w * scale * w.w);
    *(ushort4*)(Hout + (size_t)s * ldh + tid * 4) = *(ushort4*)o;
    if (tid < 64) Hout[(size_t)s * ldh + Dm + tid] = 0;   // zero 1024..1088
}

// -------- pack la matrices into MFMA B-fragment chunks (bf16) ---------------
__global__ __launch_bounds__(256) void lora_prep(
    const float* __restrict__ qla, const float* __restrict__ kla,
    const float* __restrict__ vla, const float* __restrict__ ola,
    const float* __restrict__ gla, const float* __restrict__ ula,
    const float* __restrict__ dla, unsigned short* __restrict__ lapk)
{
    int tid = threadIdx.x;
    int chunk = blockIdx.x * 4 + (tid >> 6);
    int lane = tid & 63;
    int lr = lane & 15, quad = lane >> 4;
    const float* la;
    int lc;
    if (chunk < 192) {
        int m = chunk >> 5; lc = chunk & 31;
        la = (m == 0) ? qla : (m == 1) ? kla : (m == 2) ? vla
           : (m == 3) ? ola : (m == 4) ? gla : ula;
    } else {
        la = dla; lc = chunk - 192;
    }
    alignas(16) unsigned short out[8];
#pragma unroll
    for (int e = 0; e < 8; ++e)
        out[e] = f2bf(la[(size_t)(lc * 32 + quad * 8 + e) * 16 + lr]);
    *(uint4*)(lapk + (size_t)chunk * 512 + lane * 8) = *(uint4*)out;
}

// -------- T = A @ la via MFMA; 16-row strips, 4-way wave K-split ------------
template<int NM>
__global__ __launch_bounds__(256) void lora_mfma(
    unsigned short* Aext, int lda, int K,
    const unsigned short* __restrict__ lapk, int c0, int c1, int c2,
    int toff, int zoff, int zn)
{
    int tid = threadIdx.x;
    int lane = tid & 63, wave = tid >> 6;
    int lr = lane & 15, quad = lane >> 4;
    int r0 = blockIdx.x * 16;
    int nc4 = K >> 7;                       // chunks per wave
    int gc0 = wave * nc4;
    const unsigned short* Ab = Aext + (size_t)(r0 + lr) * lda + quad * 8;
    int cb[3] = {c0, c1, c2};
    f32x4 zero = {0.f, 0.f, 0.f, 0.f};
    f32x4 acc[NM];
#pragma unroll
    for (int m = 0; m < NM; ++m) acc[m] = zero;
    for (int cc = 0; cc < nc4; ++cc) {
        int gc = gc0 + cc;
        bf16x8 af = *(const bf16x8*)(Ab + gc * 32);
#pragma unroll
        for (int m = 0; m < NM; ++m) {
            bf16x8 bf = *(const bf16x8*)(lapk + (size_t)(cb[m] + gc) * 512 + lane * 8);
            acc[m] = __builtin_amdgcn_mfma_f32_16x16x32_bf16(af, bf, acc[m], 0, 0, 0);
        }
    }
    __shared__ float red[3][NM * 64 * 4];
    if (wave > 0) {
#pragma unroll
        for (int m = 0; m < NM; ++m)
#pragma unroll
            for (int r = 0; r < 4; ++r)
                red[wave - 1][(m * 64 + lane) * 4 + r] = acc[m][r];
    }
    __syncthreads();
    if (wave == 0) {
#pragma unroll
        for (int m = 0; m < NM; ++m)
#pragma unroll
            for (int r = 0; r < 4; ++r)
                acc[m][r] += red[0][(m * 64 + lane) * 4 + r]
                           + red[1][(m * 64 + lane) * 4 + r]
                           + red[2][(m * 64 + lane) * 4 + r];
#pragma unroll
        for (int r = 0; r < 4; ++r) {
            int row = r0 + quad * 4 + r;
#pragma unroll
            for (int m = 0; m < NM; ++m)
                Aext[(size_t)row * lda + toff + m * 16 + lr] = f2bf(acc[m][r]);
        }
        if (zn > 0) {
            int row = r0 + lr, j0 = quad * 4;
            for (int j = j0; j < zn; j += 64) {
                alignas(8) unsigned short z4[4] = {0, 0, 0, 0};
                *(ushort4*)(Aext + (size_t)row * lda + zoff + j) = *(ushort4*)z4;
            }
        }
    }
}

// ---------------- NF4 dequant helpers (bf16, K-extended rows) ---------------
__device__ inline void dq_row8(const float* lut, const int* cod, const float* am,
                               const float* lb, int nr, int c8, int K, int Nlb,
                               int toff, unsigned short* out)
{
    if (c8 < K) {
        size_t base = (size_t)nr * K + c8;
        const int4* cp = (const int4*)(cod + base);
        int4 ca = cp[0], cb = cp[1];
        float a = am[base >> 6];
        out[0] = f2bf(lut[ca.x] * a); out[1] = f2bf(lut[ca.y] * a);
        out[2] = f2bf(lut[ca.z] * a); out[3] = f2bf(lut[ca.w] * a);
        out[4] = f2bf(lut[cb.x] * a); out[5] = f2bf(lut[cb.y] * a);
        out[6] = f2bf(lut[cb.z] * a); out[7] = f2bf(lut[cb.w] * a);
    } else {
        int r = c8 - toff;
#pragma unroll
        for (int i = 0; i < 8; ++i) out[i] = 0;
        if (r >= 0 && r < 16) {
#pragma unroll
            for (int i = 0; i < 8; ++i) out[i] = f2bf(lb[(size_t)(r + i) * Nlb + nr]);
        }
    }
}

// q/k/v fused: W rows [0,1024)=q, [1024,2048)=k, [2048,3072)=v ; ldw=KE1
__global__ __launch_bounds__(256) void dequant_qkv(
    const int* __restrict__ qc, const int* __restrict__ kc, const int* __restrict__ vc,
    const float* __restrict__ qa, const float* __restrict__ ka, const float* __restrict__ va,
    const float* __restrict__ qlb, const float* __restrict__ klb, const float* __restrict__ vlb,
    unsigned short* __restrict__ Wout)
{
    __shared__ float lut[16];
    if (threadIdx.x < 16) lut[threadIdx.x] = NF4_LUT[threadIdx.x];
    __syncthreads();
    int idx = blockIdx.x * 256 + threadIdx.x;        // 3072*136
    int n = idx / 136;
    int c8 = (idx - n * 136) * 8;
    int seg = n >> 10, nr = n & 1023;
    const int* cod   = (seg == 0) ? qc : (seg == 1) ? kc : vc;
    const float* am  = (seg == 0) ? qa : (seg == 1) ? ka : va;
    const float* lb  = (seg == 0) ? qlb : (seg == 1) ? klb : vlb;
    int toff = 1024 + (seg << 4);
    alignas(16) unsigned short out[8];
    dq_row8(lut, cod, am, lb, nr, c8, 1024, 1024, toff, out);
    *(uint4*)(Wout + (size_t)n * KE1 + c8) = *(uint4*)out;
}

// gate/up fused + interleaved, ROTATED layout: stride 1088 (aligned rows),
// physical 64B chunk = (virtual + row) % 34. Virtual cols: 0..1023 dequant,
// 1024+mat*16..+16 = lb^T, rest zero.
__global__ __launch_bounds__(256) void dequant_gu(
    const int* __restrict__ gc, const int* __restrict__ uc,
    const float* __restrict__ ga, const float* __restrict__ ua,
    const float* __restrict__ glb, const float* __restrict__ ulb,
    unsigned short* __restrict__ Wout)
{
    __shared__ float lut[16];
    if (threadIdx.x < 16) lut[threadIdx.x] = NF4_LUT[threadIdx.x];
    __syncthreads();
    int idx = blockIdx.x * 256 + threadIdx.x;        // 5632*136
    int n = idx / 136;
    int v8 = idx - n * 136;                          // 16B unit 0..135
    int m = n >> 1, mat = n & 1;
    const int* cod  = mat ? uc : gc;
    const float* am = mat ? ua : ga;
    const float* lb = mat ? ulb : glb;
    int toff = 1024 + (mat << 4);
    alignas(16) unsigned short out[8];
    dq_row8(lut, cod, am, lb, m, v8 * 8, 1024, Fm, toff, out);
    int ch = v8 >> 2, sub = v8 & 3;
    int ph = ch + (n % 34); if (ph >= 34) ph -= 34;
    *(uint4*)(Wout + (size_t)n * LGW + ph * 32 + sub * 8) = *(uint4*)out;
}

// generic (o-proj, down)
__global__ __launch_bounds__(256) void dequant_ext(
    const int* __restrict__ codes, const float* __restrict__ absmax,
    const float* __restrict__ lb, unsigned short* __restrict__ Wout,
    int Nproj, int K, int ldw, int toff)
{
    __shared__ float lut[16];
    if (threadIdx.x < 16) lut[threadIdx.x] = NF4_LUT[threadIdx.x];
    __syncthreads();
    int idx = blockIdx.x * 256 + threadIdx.x;
    int cpr = ldw >> 3;
    int n = idx / cpr;
    if (n >= Nproj) return;
    int c8 = (idx - n * cpr) * 8;
    alignas(16) unsigned short out[8];
    dq_row8(lut, codes, absmax, lb, n, c8, K, Nproj, toff, out);
    *(uint4*)(Wout + (size_t)n * ldw + c8) = *(uint4*)out;
}

// ------------------- GEMM 128x128, dbuf, bf16-out (qkv) ---------------------
__global__ __launch_bounds__(256) void gemm128(
    const unsigned short* __restrict__ A, int lda,
    const unsigned short* __restrict__ B, int ldb, int K,
    unsigned short* __restrict__ Cb, int ldc)
{
    __shared__ __align__(16) unsigned short At[2][128 * 32];
    __shared__ __align__(16) unsigned short Bt[2][128 * 32];
    int tid = threadIdx.x;
    int lane = tid & 63, wave = tid >> 6;
    int lr = lane & 15, quad = lane >> 4;
    int wm = (wave >> 1) * 64, wn = (wave & 1) * 64;
    int row0 = blockIdx.y * 128, col0 = blockIdx.x * 128;
    f32x4 acc[4][4];
    f32x4 zero = {0.f, 0.f, 0.f, 0.f};
#pragma unroll
    for (int i = 0; i < 4; ++i)
#pragma unroll
        for (int j = 0; j < 4; ++j) acc[i][j] = zero;
    int sw = ((tid & 3) ^ ((tid >> 3) & 3)) * 8;
    const unsigned short* Ag  = A + (size_t)(row0 + (tid >> 2)) * lda + sw;
    const unsigned short* Ag2 = Ag + (size_t)64 * lda;
    const unsigned short* Bg  = B + (size_t)(col0 + (tid >> 2)) * ldb + sw;
    const unsigned short* Bg2 = Bg + (size_t)64 * ldb;
    int l0 = tid * 8, l1 = (tid + 256) * 8;
    GLD16(Ag, At[0] + l0); GLD16(Ag2, At[0] + l1);
    GLD16(Bg, Bt[0] + l0); GLD16(Bg2, Bt[0] + l1);
    int sq = (quad ^ ((lr >> 1) & 3)) * 8;
    int nIter = K >> 5;
    for (int it = 0; it < nIter; ++it) {
        int cur = it & 1;
        __syncthreads();
        if (it + 1 < nIter) {
            int k = (it + 1) << 5, nx = cur ^ 1;
            GLD16(Ag + k, At[nx] + l0); GLD16(Ag2 + k, At[nx] + l1);
            GLD16(Bg + k, Bt[nx] + l0); GLD16(Bg2 + k, Bt[nx] + l1);
        }
        bf16x8 af[4], bfr[4];
#pragma unroll
        for (int i = 0; i < 4; ++i)
            af[i] = *(const bf16x8*)(At[cur] + (wm + i * 16 + lr) * 32 + sq);
#pragma unroll
        for (int j = 0; j < 4; ++j)
            bfr[j] = *(const bf16x8*)(Bt[cur] + (wn + j * 16 + lr) * 32 + sq);
#pragma unroll
        for (int i = 0; i < 4; ++i)
#pragma unroll
            for (int j = 0; j < 4; ++j)
                acc[i][j] = __builtin_amdgcn_mfma_f32_16x16x32_bf16(af[i], bfr[j], acc[i][j], 0, 0, 0);
    }
#pragma unroll
    for (int i = 0; i < 4; ++i) {
        int rowb = row0 + wm + i * 16 + quad * 4;
#pragma unroll
        for (int j = 0; j < 4; ++j) {
            int col = col0 + wn + j * 16 + lr;
#pragma unroll
            for (int r = 0; r < 4; ++r)
                Cb[(size_t)(rowb + r) * ldc + col] = f2bf(acc[i][j][r]);
        }
    }
}

// --- GEMM 128x128, dbuf, SwiGLU epilogue (gate/up); B rows ROTATED ----------
// B row n stride 1088; virtual chunk it lives at physical (it + n) % 34.
__global__ __launch_bounds__(256) void gemm_gu(
    const unsigned short* __restrict__ A, int lda,
    const unsigned short* __restrict__ B, int ldb, int K,
    unsigned short* __restrict__ Hb)
{
    __shared__ __align__(16) unsigned short At[2][128 * 32];
    __shared__ __align__(16) unsigned short Bt[2][128 * 32];
    int tid = threadIdx.x;
    int lane = tid & 63, wave = tid >> 6;
    int lr = lane & 15, quad = lane >> 4;
    int wm = (wave >> 1) * 64, wn = (wave & 1) * 64;
    int row0 = blockIdx.y * 128, col0 = blockIdx.x * 128;
    f32x4 acc[4][4];
    f32x4 zero = {0.f, 0.f, 0.f, 0.f};
#pragma unroll
    for (int i = 0; i < 4; ++i)
#pragma unroll
        for (int j = 0; j < 4; ++j) acc[i][j] = zero;
    int sw = ((tid & 3) ^ ((tid >> 3) & 3)) * 8;
    const unsigned short* Ag  = A + (size_t)(row0 + (tid >> 2)) * lda + sw;
    const unsigned short* Ag2 = Ag + (size_t)64 * lda;
    int rB  = col0 + (tid >> 2);
    const unsigned short* Bb  = B + (size_t)rB * ldb + sw;
    const unsigned short* Bb2 = B + (size_t)(rB + 64) * ldb + sw;
    int cB  = rB % 34;                       // physical chunk of virtual 0
    int cB2 = (rB + 64) % 34;
    int l0 = tid * 8, l1 = (tid + 256) * 8;
    GLD16(Ag, At[0] + l0); GLD16(Ag2, At[0] + l1);
    GLD16(Bb + cB * 32, Bt[0] + l0);
    GLD16(Bb2 + cB2 * 32, Bt[0] + l1);
    cB  = (cB + 1 == 34) ? 0 : cB + 1;
    cB2 = (cB2 + 1 == 34) ? 0 : cB2 + 1;
    int sq = (quad ^ ((lr >> 1) & 3)) * 8;
    int nIter = K >> 5;                      // 34
    for (int it = 0; it < nIter; ++it) {
        int cur = it & 1;
        __syncthreads();
        if (it + 1 < nIter) {
            int k = (it + 1) << 5, nx = cur ^ 1;
            GLD16(Ag + k, At[nx] + l0); GLD16(Ag2 + k, At[nx] + l1);
            GLD16(Bb + cB * 32, Bt[nx] + l0);
            GLD16(Bb2 + cB2 * 32, Bt[nx] + l1);
            cB  = (cB + 1 == 34) ? 0 : cB + 1;
            cB2 = (cB2 + 1 == 34) ? 0 : cB2 + 1;
        }
        bf16x8 af[4], bfr[4];
#pragma unroll
        for (int i = 0; i < 4; ++i)
            af[i] = *(const bf16x8*)(At[cur] + (wm + i * 16 + lr) * 32 + sq);
#pragma unroll
        for (int j = 0; j < 4; ++j)
            bfr[j] = *(const bf16x8*)(Bt[cur] + (wn + j * 16 + lr) * 32 + sq);
#pragma unroll
        for (int i = 0; i < 4; ++i)
#pragma unroll
            for (int j = 0; j < 4; ++j)
                acc[i][j] = __builtin_amdgcn_mfma_f32_16x16x32_bf16(af[i], bfr[j], acc[i][j], 0, 0, 0);
    }
#pragma unroll
    for (int i = 0; i < 4; ++i) {
        int rowb = row0 + wm + i * 16 + quad * 4;
#pragma unroll
        for (int j = 0; j < 4; ++j) {
            int col = col0 + wn + j * 16 + lr;     // even=gate, odd=up
#pragma unroll
            for (int r = 0; r < 4; ++r) {
                float own = acc[i][j][r];
                float oth = __shfl_xor(own, 1);
                if (!(lr & 1)) {
                    float sig = 1.0f / (1.0f + __expf(-own));
                    Hb[(size_t)(rowb + r) * KE3 + (col >> 1)] = f2bf(oth * own * sig);
                }
            }
        }
    }
}

// ------ GEMM 64x64, BK=64 dbuf, f32 + residual out (o, down) ----------------
template<int TAG>
__global__ __launch_bounds__(256) void gemm_s(
    const unsigned short* __restrict__ A, int lda,
    const unsigned short* __restrict__ B, int ldb, int K,
    float* __restrict__ Cf, int ldc, const float* __restrict__ Radd)
{
    __shared__ __align__(16) unsigned short At[2][64 * 64];
    __shared__ __align__(16) unsigned short Bt[2][64 * 64];
    int tid = threadIdx.x;
    int lane = tid & 63, wave = tid >> 6;
    int lr = lane & 15, quad = lane >> 4;
    int row0 = blockIdx.y * 64, col0 = blockIdx.x * 64;
    f32x4 acc[4];
    f32x4 zero = {0.f, 0.f, 0.f, 0.f};
#pragma unroll
    for (int j = 0; j < 4; ++j) acc[j] = zero;
    int rs = tid >> 3;
    int g8 = ((tid & 7) ^ (rs & 7)) * 8;
    const unsigned short* Ag  = A + (size_t)(row0 + rs) * lda + g8;
    const unsigned short* Ag2 = Ag + (size_t)32 * lda;
    const unsigned short* Bg  = B + (size_t)(col0 + rs) * ldb + g8;
    const unsigned short* Bg2 = Bg + (size_t)32 * ldb;
    int l0 = tid * 8, l1 = (tid + 256) * 8;
    GLD16(Ag, At[0] + l0); GLD16(Ag2, At[0] + l1);
    GLD16(Bg, Bt[0] + l0); GLD16(Bg2, Bt[0] + l1);
    int c0 = (quad ^ (lr & 7)) * 8;
    int c1 = ((4 + quad) ^ (lr & 7)) * 8;
    int nIter = K >> 6;
    for (int it = 0; it < nIter; ++it) {
        int cur = it & 1;
        __syncthreads();
        if (it + 1 < nIter) {
            int k = (it + 1) << 6, nx = cur ^ 1;
            GLD16(Ag + k, At[nx] + l0); GLD16(Ag2 + k, At[nx] + l1);
            GLD16(Bg + k, Bt[nx] + l0); GLD16(Bg2 + k, Bt[nx] + l1);
        }
        const unsigned short* arow = At[cur] + (wave * 16 + lr) * 64;
        bf16x8 a0 = *(const bf16x8*)(arow + c0);
        bf16x8 a1 = *(const bf16x8*)(arow + c1);
        bf16x8 b0[4], b1[4];
#pragma unroll
        for (int j = 0; j < 4; ++j) {
            const unsigned short* brow = Bt[cur] + (j * 16 + lr) * 64;
            b0[j] = *(const bf16x8*)(brow + c0);
            b1[j] = *(const bf16x8*)(brow + c1);
        }
#pragma unroll
        for (int j = 0; j < 4; ++j) {
            acc[j] = __builtin_amdgcn_mfma_f32_16x16x32_bf16(a0, b0[j], acc[j], 0, 0, 0);
            acc[j] = __builtin_amdgcn_mfma_f32_16x16x32_bf16(a1, b1[j], acc[j], 0, 0, 0);
        }
    }
    int rowb = row0 + wave * 16 + quad * 4;
#pragma unroll
    for (int j = 0; j < 4; ++j) {
        int col = col0 + j * 16 + lr;
#pragma unroll
        for (int r = 0; r < 4; ++r) {
            size_t o = (size_t)(rowb + r) * ldc + col;
            Cf[o] = acc[j][r] + Radd[o];
        }
    }
}

// -------- fused rope(q) + rope+fragment-pack(K) + fragment-pack(V) ----------
__global__ __launch_bounds__(256) void rope_pack(
    const unsigned short* __restrict__ qkv,
    const float* __restrict__ cosT, const float* __restrict__ sinT,
    const int* __restrict__ pos,
    unsigned short* __restrict__ qb, unsigned short* __restrict__ kpk,
    unsigned short* __restrict__ vpk)
{
    int b = blockIdx.x, tid = threadIdx.x;
    if (b < 8192) {                              // Q rope (coalesced write)
        int idx = b * 256 + tid;                 // over 2048*1024
        int s = idx >> 10, col = idx & 1023, d = col & 63;
        int p = pos[s];
        float c = cosT[p * 64 + d], sn = sinT[p * 64 + d];
        int partner = (d < 32) ? (col + 32) : (col - 32);
        float sgn = (d < 32) ? -1.f : 1.f;
        const unsigned short* row = qkv + (size_t)s * NQKV;
        float q = bf2f(row[col]), q2 = bf2f(row[partner]);
        qb[idx] = f2bf((q * c + sgn * q2 * sn) * 0.125f);
    } else if (b < 9216) {                       // K rope + pack, 16B/thread
        int g = (b - 8192) * 256 + tid;          // 0..262143
        int lr = g & 15, quad = (g >> 4) & 3, cch = (g >> 6) & 1;
        int t = (g >> 7) & 127, h = g >> 14;
        int s = t * 16 + lr;
        int p = pos[s];
        int d0 = cch * 32 + quad * 8;
        const unsigned short* krow = qkv + (size_t)s * NQKV + Dm + h * 64;
        uint4 kv8 = *(const uint4*)(krow + d0);
        uint4 kp8 = *(const uint4*)(krow + ((d0 + 32) & 63));
        float sgn = (d0 < 32) ? -1.f : 1.f;
        const float* cp = cosT + p * 64 + d0;
        const float* sp = sinT + p * 64 + d0;
        const unsigned short* ke = (const unsigned short*)&kv8;
        const unsigned short* pe = (const unsigned short*)&kp8;
        alignas(16) unsigned short out[8];
#pragma unroll
        for (int e = 0; e < 8; ++e)
            out[e] = f2bf(bf2f(ke[e]) * cp[e] + sgn * bf2f(pe[e]) * sp[e]);
        *(uint4*)(kpk + (size_t)g * 8) = *(uint4*)out;
    } else {                                     // V pack, 16B/thread
        int g = (b - 9216) * 256 + tid;          // 0..262143
        int lrr = g & 15, quad = (g >> 4) & 3, kk = (g >> 6) & 3;
        int j = (g >> 8) & 3, kt = (g >> 10) & 15, h = g >> 14;
        int d = j * 16 + lrr;
        int sbase = kt * 128 + kk * 32 + quad * 8;
        alignas(16) unsigned short out[8];
#pragma unroll
        for (int e = 0; e < 8; ++e)
            out[e] = qkv[(size_t)(sbase + e) * NQKV + 2048 + h * 64 + d];
        *(uint4*)(vpk + (size_t)g * 8) = *(uint4*)out;
    }
}

// ------------- flash attention: packed frags, no-max softmax ----------------
__global__ __launch_bounds__(256) void attn(
    const unsigned short* __restrict__ qb, const unsigned short* __restrict__ kpk,
    const unsigned short* __restrict__ vpk, unsigned short* __restrict__ ob)
{
    __shared__ __align__(16) unsigned short Ps[4][16 * 136];
    int tid = threadIdx.x;
    int lane = tid & 63, wave = tid >> 6;
    int lr = lane & 15, quad = lane >> 4;
    int idx = blockIdx.x;
    int t_ = idx >> 4;
    int qt = (idx < 256) ? (31 - t_) : (t_ - 16);
    int h = idx & 15;
    int r0 = qt * 64 + wave * 16;
    const unsigned short* qp = qb + (size_t)(r0 + lr) * Dm + h * 64 + quad * 8;
    bf16x8 qf0 = *(const bf16x8*)qp;
    bf16x8 qf1 = *(const bf16x8*)(qp + 32);
    const unsigned short* kpb = kpk + (size_t)h * 128 * 1024 + lane * 8;
    const unsigned short* vpb = vpk + (size_t)h * 16 * 16 * 512 + lane * 8;
    f32x4 zero = {0.f, 0.f, 0.f, 0.f};
    f32x4 oacc[4];
#pragma unroll
    for (int j = 0; j < 4; ++j) oacc[j] = zero;
    float lrow[4] = {0.f, 0.f, 0.f, 0.f};
    int ntile = (qt * 64 + 191) >> 7;

    for (int kt = 0; kt < ntile; ++kt) {
        int k0 = kt << 7;
        f32x4 sf[8];
#pragma unroll
        for (int jj = 0; jj < 8; ++jj) {
            const unsigned short* kp = kpb + (size_t)(kt * 8 + jj) * 1024;
            bf16x8 kf0 = *(const bf16x8*)kp;
            bf16x8 kf1 = *(const bf16x8*)(kp + 512);
            f32x4 z = zero;
            z = __builtin_amdgcn_mfma_f32_16x16x32_bf16(qf0, kf0, z, 0, 0, 0);
            z = __builtin_amdgcn_mfma_f32_16x16x32_bf16(qf1, kf1, z, 0, 0, 0);
            sf[jj] = z;
        }
        bf16x8 vf[4][4];
#pragma unroll
        for (int j = 0; j < 4; ++j)
#pragma unroll
            for (int kk = 0; kk < 4; ++kk)
                vf[j][kk] = *(const bf16x8*)(vpb + (size_t)((kt * 4 + j) * 4 + kk) * 512);
        if (kt == ntile - 1) {
#pragma unroll
            for (int jj = 0; jj < 8; ++jj)
#pragma unroll
                for (int r = 0; r < 4; ++r)
                    if (k0 + jj * 16 + lr > r0 + quad * 4 + r)
                        sf[jj][r] = -1e30f;
        }
#pragma unroll
        for (int jj = 0; jj < 8; ++jj)
#pragma unroll
            for (int r = 0; r < 4; ++r) {
                float p = __expf(sf[jj][r]);
                sf[jj][r] = p;
                lrow[r] += p;
            }
#pragma unroll
        for (int jj = 0; jj < 8; ++jj)
#pragma unroll
            for (int r = 0; r < 4; ++r)
                Ps[wave][(quad * 4 + r) * 136 + jj * 16 + lr] = truncbf(sf[jj][r]);
        bf16x8 pf[4];
#pragma unroll
        for (int kk = 0; kk < 4; ++kk)
            pf[kk] = *(const bf16x8*)(&Ps[wave][lr * 136 + kk * 32 + quad * 8]);
#pragma unroll
        for (int j = 0; j < 4; ++j)
#pragma unroll
            for (int kk = 0; kk < 4; ++kk)
                oacc[j] = __builtin_amdgcn_mfma_f32_16x16x32_bf16(pf[kk], vf[j][kk], oacc[j], 0, 0, 0);
    }
#pragma unroll
    for (int r = 0; r < 4; ++r)
#pragma unroll
        for (int m = 1; m < 16; m <<= 1) lrow[r] += __shfl_xor(lrow[r], m);
#pragma unroll
    for (int r = 0; r < 4; ++r) {
        float inv = 1.0f / lrow[r];
        int row = r0 + quad * 4 + r;
#pragma unroll
        for (int j = 0; j < 4; ++j)
            ob[(size_t)row * KE2 + h * 64 + j * 16 + lr] = f2bf(oacc[j][r] * inv);
    }
}

// ---------------------------------------------------------------------------
extern "C" void kernel_launch(void* const* d_in, const int* in_sizes, int n_in,
                              void* d_out, int out_size, void* d_ws, size_t ws_size,
                              hipStream_t stream)
{
    const float* x    = (const float*)d_in[0];
    const float* nw1  = (const float*)d_in[1];
    const float* nw2  = (const float*)d_in[2];
    const float* cosT = (const float*)d_in[3];
    const float* sinT = (const float*)d_in[4];
    const int*   pos  = (const int*)d_in[5];
    const int   *qc = (const int*)d_in[6],  *kc = (const int*)d_in[10],
                *vc = (const int*)d_in[14], *oc = (const int*)d_in[18],
                *gc = (const int*)d_in[22], *uc = (const int*)d_in[26],
                *dc = (const int*)d_in[30];
    const float *qa = (const float*)d_in[7],  *ka = (const float*)d_in[11],
                *va = (const float*)d_in[15], *oa = (const float*)d_in[19],
                *ga = (const float*)d_in[23], *ua = (const float*)d_in[27],
                *da = (const float*)d_in[31];
    const float *qla = (const float*)d_in[8],  *kla = (const float*)d_in[12],
                *vla = (const float*)d_in[16], *ola = (const float*)d_in[20],
                *gla = (const float*)d_in[24], *ula = (const float*)d_in[28],
                *dla = (const float*)d_in[32];
    const float *qlb = (const float*)d_in[9],  *klb = (const float*)d_in[13],
                *vlb = (const float*)d_in[17], *olb = (const float*)d_in[21],
                *glb = (const float*)d_in[25], *ulb = (const float*)d_in[29],
                *dlb = (const float*)d_in[33];

    // workspace (peak ~58.4 MB; x1 overlays qbf+kpk which die after attn)
    char* ws = (char*)d_ws;
    unsigned short* h    = (unsigned short*)(ws + 0);          // [2048,1088]
    unsigned short* W    = (unsigned short*)(ws + 4456448);    // <= [5632,1088]
    unsigned short* qkv  = (unsigned short*)(ws + 16711680);   // [2048,3072]
    unsigned short* qbf  = (unsigned short*)(ws + 29294592);   // [2048,1024]
    unsigned short* kpk  = (unsigned short*)(ws + 33488896);   // 4 MB
    unsigned short* vpk  = (unsigned short*)(ws + 37683200);   // 4 MB
    unsigned short* obf  = (unsigned short*)(ws + 41877504);   // [2048,1088]
    float*          x1   = (float*)(ws + 29294592);            // overlays qbf+kpk
    unsigned short* hb   = (unsigned short*)(ws + 46333952);   // [2048,2880]
    unsigned short* lapk = (unsigned short*)(ws + 58130432);   // 280 x 1KB
    float* outp = (float*)d_out;

    // ---- attention block ----
    lora_prep<<<70, 256, 0, stream>>>(qla, kla, vla, ola, gla, ula, dla, lapk);
    rmsnorm_ext<<<Sq, 256, 0, stream>>>(x, nw1, h, KE1);
    lora_mfma<3><<<128, 256, 0, stream>>>(h, KE1, Dm, lapk, 0, 32, 64, 1024, 0, 0);
    dequant_qkv<<<1632, 256, 0, stream>>>(qc, kc, vc, qa, ka, va, qlb, klb, vlb, W);
    gemm128<<<dim3(NQKV / 128, Sq / 128), 256, 0, stream>>>(h, KE1, W, KE1, KE1, qkv, NQKV);
    rope_pack<<<10240, 256, 0, stream>>>(qkv, cosT, sinT, pos, qbf, kpk, vpk);
    attn<<<512, 256, 0, stream>>>(qbf, kpk, vpk, obf);
    lora_mfma<1><<<128, 256, 0, stream>>>(obf, KE2, Dm, lapk, 96, 0, 0, 1024, 1040, 16);
    dequant_ext<<<544, 256, 0, stream>>>(oc, oa, olb, W, Dm, Dm, KE2, 1024);
    gemm_s<0><<<dim3(Dm / 64, Sq / 64), 256, 0, stream>>>(obf, KE2, W, KE2, KE2, x1, Dm, x);
    // ---- MLP block ----
    rmsnorm_ext<<<Sq, 256, 0, stream>>>(x1, nw2, h, KE1);
    lora_mfma<2><<<128, 256, 0, stream>>>(h, KE1, Dm, lapk, 128, 160, 0, 1024, 0, 0);
    dequant_gu<<<2992, 256, 0, stream>>>(gc, uc, ga, ua, glb, ulb, W);
    gemm_gu<<<dim3(NGU / 128, Sq / 128), 256, 0, stream>>>(h, KE1, W, LGW, LGW, hb);
    lora_mfma<1><<<128, 256, 0, stream>>>(hb, KE3, Fm, lapk, 192, 0, 0, 2816, 2832, 16);
    dequant_ext<<<1440, 256, 0, stream>>>(dc, da, dlb, W, Dm, Fm, KE3, 2816);
    gemm_s<1><<<dim3(Dm / 64, Sq / 64), 256, 0, stream>>>(hb, KE3, W, KE3, KE3, outp, Dm, x1);
}

// Round 18
// 341.269 us; speedup vs baseline: 1.0515x; 1.0112x over previous
//
#include <hip/hip_runtime.h>
#include <stdint.h>

// ---------------------------------------------------------------------------
// MixedSparseSingleLayerWithGate: NF4-dequant QLoRA transformer layer, MI355X.
// R18 = R17 + launch-count reduction: lora_prep + all 4 dequants merged into
// one 6678-block prep_weights kernel (19 -> 13 dispatches). Requires disjoint
// W storage: Wq+Wo overlay hb (dead until gemm_gu), Wgu in the old W slot,
// Wd in a new 5.9MB tail. Peak ws 64.3MB (<65.9MB proven in R1-5).
// All compute kernels byte-identical to R17.
// ---------------------------------------------------------------------------

#define Sq   2048
#define Dm   1024
#define Fm   2816
#define Hh   16
#define KE1  1088   // h & W_qkv stride / qkv & o reduction
#define KE2  1088   // obf & W_o stride
#define LGW  1088   // gate/up W stride (rotated rows), reduction K = 1088
#define KE3  2880   // hb & W_down stride / down reduction
#define NQKV 3072
#define NGU  5632

typedef short bf16x8 __attribute__((ext_vector_type(8)));
typedef float f32x4  __attribute__((ext_vector_type(4)));

__constant__ float NF4_LUT[16] = {
    -1.0f, -0.6961928009986877f, -0.5250730514526367f, -0.39491748809814453f,
    -0.28444138169288635f, -0.18477343022823334f, -0.09105003625154495f, 0.0f,
    0.07958029955625534f, 0.16093020141124725f, 0.24611230194568634f,
    0.33791524171829224f, 0.44070982933044434f, 0.5626170039176941f,
    0.7229568362236023f, 1.0f};

__device__ inline unsigned short f2bf(float f) {
    union { float f; uint32_t u; } v; v.f = f;
    uint32_t u = v.u;
    return (unsigned short)((u + 0x7FFFu + ((u >> 16) & 1u)) >> 16);
}
__device__ inline float bf2f(unsigned short h) {
    union { uint32_t u; float f; } v; v.u = ((uint32_t)h) << 16;
    return v.f;
}
__device__ inline unsigned short truncbf(float f) {
    union { float f; uint32_t u; } v; v.f = f;
    return (unsigned short)(v.u >> 16);
}

// async global->LDS, 16 B per lane; LDS dest = wave-uniform base + lane*16
#define GLD16(gp, lp)                                                         \
    __builtin_amdgcn_global_load_lds(                                         \
        (__attribute__((address_space(1))) void*)(uintptr_t)(gp),             \
        (__attribute__((address_space(3))) void*)(uint32_t)(uintptr_t)(lp),   \
        16, 0, 0)

// --------------------------- rmsnorm -> bf16 ext -----------------------------
__global__ __launch_bounds__(256) void rmsnorm_ext(
    const float* __restrict__ X, const float* __restrict__ W,
    unsigned short* Hout, int ldh)
{
    int s = blockIdx.x, tid = threadIdx.x;
    const float4 v = *(const float4*)(X + (size_t)s * Dm + tid * 4);
    float ss = v.x * v.x + v.y * v.y + v.z * v.z + v.w * v.w;
#pragma unroll
    for (int m = 1; m < 64; m <<= 1) ss += __shfl_xor(ss, m);
    __shared__ float red[4];
    int lane = tid & 63, wave = tid >> 6;
    if (lane == 0) red[wave] = ss;
    __syncthreads();
    float scale = rsqrtf((red[0] + red[1] + red[2] + red[3]) * (1.0f / Dm) + 1e-10f);
    const float4 w = *(const float4*)(W + tid * 4);
    alignas(8) unsigned short o[4];
    o[0] = f2bf(v.x * scale * w.x);
    o[1] = f2bf(v.y * scale * w.y);
    o[2] = f2bf(v.z * scale * w.z);
    o[3] = f2bf(v.w * scale * w.w);
    *(ushort4*)(Hout + (size_t)s * ldh + tid * 4) = *(ushort4*)o;
    if (tid < 64) Hout[(size_t)s * ldh + Dm + tid] = 0;   // zero 1024..1088
}

// ---------------- NF4 dequant helper (bf16, K-extended rows) ----------------
__device__ inline void dq_row8(const float* lut, const int* cod, const float* am,
                               const float* lb, int nr, int c8, int K, int Nlb,
                               int toff, unsigned short* out)
{
    if (c8 < K) {
        size_t base = (size_t)nr * K + c8;
        const int4* cp = (const int4*)(cod + base);
        int4 ca = cp[0], cb = cp[1];
        float a = am[base >> 6];
        out[0] = f2bf(lut[ca.x] * a); out[1] = f2bf(lut[ca.y] * a);
        out[2] = f2bf(lut[ca.z] * a); out[3] = f2bf(lut[ca.w] * a);
        out[4] = f2bf(lut[cb.x] * a); out[5] = f2bf(lut[cb.y] * a);
        out[6] = f2bf(lut[cb.z] * a); out[7] = f2bf(lut[cb.w] * a);
    } else {
        int r = c8 - toff;
#pragma unroll
        for (int i = 0; i < 8; ++i) out[i] = 0;
        if (r >= 0 && r < 16) {
#pragma unroll
            for (int i = 0; i < 8; ++i) out[i] = f2bf(lb[(size_t)(r + i) * Nlb + nr]);
        }
    }
}

// ---- merged weight prep: lora_prep + dequant {qkv, o, gu(rotated), down} ---
// block ranges: [0,70) lora frag pack | [70,1702) qkv | [1702,2246) o |
// [2246,5238) gu rotated | [5238,6678) down
__global__ __launch_bounds__(256) void prep_weights(
    const int* __restrict__ qc, const int* __restrict__ kc, const int* __restrict__ vc,
    const int* __restrict__ oc, const int* __restrict__ gc, const int* __restrict__ uc,
    const int* __restrict__ dc,
    const float* __restrict__ qa, const float* __restrict__ ka, const float* __restrict__ va,
    const float* __restrict__ oa, const float* __restrict__ ga, const float* __restrict__ ua,
    const float* __restrict__ da,
    const float* __restrict__ qla, const float* __restrict__ kla, const float* __restrict__ vla,
    const float* __restrict__ ola, const float* __restrict__ gla, const float* __restrict__ ula,
    const float* __restrict__ dla,
    const float* __restrict__ qlb, const float* __restrict__ klb, const float* __restrict__ vlb,
    const float* __restrict__ olb, const float* __restrict__ glb, const float* __restrict__ ulb,
    const float* __restrict__ dlb,
    unsigned short* __restrict__ lapk, unsigned short* __restrict__ Wq,
    unsigned short* __restrict__ Wo, unsigned short* __restrict__ Wgu,
    unsigned short* __restrict__ Wd)
{
    int b = blockIdx.x, tid = threadIdx.x;
    if (b < 70) {                                // ---- lora fragment pack ----
        int chunk = b * 4 + (tid >> 6);
        int lane = tid & 63;
        int lr = lane & 15, quad = lane >> 4;
        const float* la;
        int lc;
        if (chunk < 192) {
            int m = chunk >> 5; lc = chunk & 31;
            la = (m == 0) ? qla : (m == 1) ? kla : (m == 2) ? vla
               : (m == 3) ? ola : (m == 4) ? gla : ula;
        } else {
            la = dla; lc = chunk - 192;
        }
        alignas(16) unsigned short out[8];
#pragma unroll
        for (int e = 0; e < 8; ++e)
            out[e] = f2bf(la[(size_t)(lc * 32 + quad * 8 + e) * 16 + lr]);
        *(uint4*)(lapk + (size_t)chunk * 512 + lane * 8) = *(uint4*)out;
        return;
    }
    __shared__ float lut[16];
    if (tid < 16) lut[tid] = NF4_LUT[tid];
    __syncthreads();
    if (b < 1702) {                              // ---- dequant qkv ----------
        int idx = (b - 70) * 256 + tid;          // 3072*136
        int n = idx / 136;
        int c8 = (idx - n * 136) * 8;
        int seg = n >> 10, nr = n & 1023;
        const int* cod   = (seg == 0) ? qc : (seg == 1) ? kc : vc;
        const float* am  = (seg == 0) ? qa : (seg == 1) ? ka : va;
        const float* lb  = (seg == 0) ? qlb : (seg == 1) ? klb : vlb;
        int toff = 1024 + (seg << 4);
        alignas(16) unsigned short out[8];
        dq_row8(lut, cod, am, lb, nr, c8, 1024, 1024, toff, out);
        *(uint4*)(Wq + (size_t)n * KE1 + c8) = *(uint4*)out;
    } else if (b < 2246) {                       // ---- dequant o ------------
        int idx = (b - 1702) * 256 + tid;        // 1024*136
        int n = idx / 136;
        int c8 = (idx - n * 136) * 8;
        alignas(16) unsigned short out[8];
        dq_row8(lut, oc, oa, olb, n, c8, 1024, Dm, 1024, out);
        *(uint4*)(Wo + (size_t)n * KE2 + c8) = *(uint4*)out;
    } else if (b < 5238) {                       // ---- dequant gu (rotated) -
        int idx = (b - 2246) * 256 + tid;        // 5632*136
        int n = idx / 136;
        int v8 = idx - n * 136;
        int m = n >> 1, mat = n & 1;
        const int* cod  = mat ? uc : gc;
        const float* am = mat ? ua : ga;
        const float* lb = mat ? ulb : glb;
        int toff = 1024 + (mat << 4);
        alignas(16) unsigned short out[8];
        dq_row8(lut, cod, am, lb, m, v8 * 8, 1024, Fm, toff, out);
        int ch = v8 >> 2, sub = v8 & 3;
        int ph = ch + (n % 34); if (ph >= 34) ph -= 34;
        *(uint4*)(Wgu + (size_t)n * LGW + ph * 32 + sub * 8) = *(uint4*)out;
    } else {                                     // ---- dequant down ---------
        int idx = (b - 5238) * 256 + tid;        // 1024*360
        int n = idx / 360;
        if (n >= Dm) return;
        int c8 = (idx - n * 360) * 8;
        alignas(16) unsigned short out[8];
        dq_row8(lut, dc, da, dlb, n, c8, 2816, Dm, 2816, out);
        *(uint4*)(Wd + (size_t)n * KE3 + c8) = *(uint4*)out;
    }
}

// -------- T = A @ la via MFMA; 16-row strips, 4-way wave K-split ------------
template<int NM>
__global__ __launch_bounds__(256) void lora_mfma(
    unsigned short* Aext, int lda, int K,
    const unsigned short* __restrict__ lapk, int c0, int c1, int c2,
    int toff, int zoff, int zn)
{
    int tid = threadIdx.x;
    int lane = tid & 63, wave = tid >> 6;
    int lr = lane & 15, quad = lane >> 4;
    int r0 = blockIdx.x * 16;
    int nc4 = K >> 7;                       // chunks per wave
    int gc0 = wave * nc4;
    const unsigned short* Ab = Aext + (size_t)(r0 + lr) * lda + quad * 8;
    int cb[3] = {c0, c1, c2};
    f32x4 zero = {0.f, 0.f, 0.f, 0.f};
    f32x4 acc[NM];
#pragma unroll
    for (int m = 0; m < NM; ++m) acc[m] = zero;
    for (int cc = 0; cc < nc4; ++cc) {
        int gc = gc0 + cc;
        bf16x8 af = *(const bf16x8*)(Ab + gc * 32);
#pragma unroll
        for (int m = 0; m < NM; ++m) {
            bf16x8 bf = *(const bf16x8*)(lapk + (size_t)(cb[m] + gc) * 512 + lane * 8);
            acc[m] = __builtin_amdgcn_mfma_f32_16x16x32_bf16(af, bf, acc[m], 0, 0, 0);
        }
    }
    __shared__ float red[3][NM * 64 * 4];
    if (wave > 0) {
#pragma unroll
        for (int m = 0; m < NM; ++m)
#pragma unroll
            for (int r = 0; r < 4; ++r)
                red[wave - 1][(m * 64 + lane) * 4 + r] = acc[m][r];
    }
    __syncthreads();
    if (wave == 0) {
#pragma unroll
        for (int m = 0; m < NM; ++m)
#pragma unroll
            for (int r = 0; r < 4; ++r)
                acc[m][r] += red[0][(m * 64 + lane) * 4 + r]
                           + red[1][(m * 64 + lane) * 4 + r]
                           + red[2][(m * 64 + lane) * 4 + r];
#pragma unroll
        for (int r = 0; r < 4; ++r) {
            int row = r0 + quad * 4 + r;
#pragma unroll
            for (int m = 0; m < NM; ++m)
                Aext[(size_t)row * lda + toff + m * 16 + lr] = f2bf(acc[m][r]);
        }
        if (zn > 0) {
            int row = r0 + lr, j0 = quad * 4;
            for (int j = j0; j < zn; j += 64) {
                alignas(8) unsigned short z4[4] = {0, 0, 0, 0};
                *(ushort4*)(Aext + (size_t)row * lda + zoff + j) = *(ushort4*)z4;
            }
        }
    }
}

// ------------------- GEMM 128x128, dbuf, bf16-out (qkv) ---------------------
__global__ __launch_bounds__(256) void gemm128(
    const unsigned short* __restrict__ A, int lda,
    const unsigned short* __restrict__ B, int ldb, int K,
    unsigned short* __restrict__ Cb, int ldc)
{
    __shared__ __align__(16) unsigned short At[2][128 * 32];
    __shared__ __align__(16) unsigned short Bt[2][128 * 32];
    int tid = threadIdx.x;
    int lane = tid & 63, wave = tid >> 6;
    int lr = lane & 15, quad = lane >> 4;
    int wm = (wave >> 1) * 64, wn = (wave & 1) * 64;
    int row0 = blockIdx.y * 128, col0 = blockIdx.x * 128;
    f32x4 acc[4][4];
    f32x4 zero = {0.f, 0.f, 0.f, 0.f};
#pragma unroll
    for (int i = 0; i < 4; ++i)
#pragma unroll
        for (int j = 0; j < 4; ++j) acc[i][j] = zero;
    int sw = ((tid & 3) ^ ((tid >> 3) & 3)) * 8;
    const unsigned short* Ag  = A + (size_t)(row0 + (tid >> 2)) * lda + sw;
    const unsigned short* Ag2 = Ag + (size_t)64 * lda;
    const unsigned short* Bg  = B + (size_t)(col0 + (tid >> 2)) * ldb + sw;
    const unsigned short* Bg2 = Bg + (size_t)64 * ldb;
    int l0 = tid * 8, l1 = (tid + 256) * 8;
    GLD16(Ag, At[0] + l0); GLD16(Ag2, At[0] + l1);
    GLD16(Bg, Bt[0] + l0); GLD16(Bg2, Bt[0] + l1);
    int sq = (quad ^ ((lr >> 1) & 3)) * 8;
    int nIter = K >> 5;
    for (int it = 0; it < nIter; ++it) {
        int cur = it & 1;
        __syncthreads();
        if (it + 1 < nIter) {
            int k = (it + 1) << 5, nx = cur ^ 1;
            GLD16(Ag + k, At[nx] + l0); GLD16(Ag2 + k, At[nx] + l1);
            GLD16(Bg + k, Bt[nx] + l0); GLD16(Bg2 + k, Bt[nx] + l1);
        }
        bf16x8 af[4], bfr[4];
#pragma unroll
        for (int i = 0; i < 4; ++i)
            af[i] = *(const bf16x8*)(At[cur] + (wm + i * 16 + lr) * 32 + sq);
#pragma unroll
        for (int j = 0; j < 4; ++j)
            bfr[j] = *(const bf16x8*)(Bt[cur] + (wn + j * 16 + lr) * 32 + sq);
#pragma unroll
        for (int i = 0; i < 4; ++i)
#pragma unroll
            for (int j = 0; j < 4; ++j)
                acc[i][j] = __builtin_amdgcn_mfma_f32_16x16x32_bf16(af[i], bfr[j], acc[i][j], 0, 0, 0);
    }
#pragma unroll
    for (int i = 0; i < 4; ++i) {
        int rowb = row0 + wm + i * 16 + quad * 4;
#pragma unroll
        for (int j = 0; j < 4; ++j) {
            int col = col0 + wn + j * 16 + lr;
#pragma unroll
            for (int r = 0; r < 4; ++r)
                Cb[(size_t)(rowb + r) * ldc + col] = f2bf(acc[i][j][r]);
        }
    }
}

// --- GEMM 128x128, dbuf, SwiGLU epilogue (gate/up); B rows ROTATED ----------
__global__ __launch_bounds__(256) void gemm_gu(
    const unsigned short* __restrict__ A, int lda,
    const unsigned short* __restrict__ B, int ldb, int K,
    unsigned short* __restrict__ Hb)
{
    __shared__ __align__(16) unsigned short At[2][128 * 32];
    __shared__ __align__(16) unsigned short Bt[2][128 * 32];
    int tid = threadIdx.x;
    int lane = tid & 63, wave = tid >> 6;
    int lr = lane & 15, quad = lane >> 4;
    int wm = (wave >> 1) * 64, wn = (wave & 1) * 64;
    int row0 = blockIdx.y * 128, col0 = blockIdx.x * 128;
    f32x4 acc[4][4];
    f32x4 zero = {0.f, 0.f, 0.f, 0.f};
#pragma unroll
    for (int i = 0; i < 4; ++i)
#pragma unroll
        for (int j = 0; j < 4; ++j) acc[i][j] = zero;
    int sw = ((tid & 3) ^ ((tid >> 3) & 3)) * 8;
    const unsigned short* Ag  = A + (size_t)(row0 + (tid >> 2)) * lda + sw;
    const unsigned short* Ag2 = Ag + (size_t)64 * lda;
    int rB  = col0 + (tid >> 2);
    const unsigned short* Bb  = B + (size_t)rB * ldb + sw;
    const unsigned short* Bb2 = B + (size_t)(rB + 64) * ldb + sw;
    int cB  = rB % 34;
    int cB2 = (rB + 64) % 34;
    int l0 = tid * 8, l1 = (tid + 256) * 8;
    GLD16(Ag, At[0] + l0); GLD16(Ag2, At[0] + l1);
    GLD16(Bb + cB * 32, Bt[0] + l0);
    GLD16(Bb2 + cB2 * 32, Bt[0] + l1);
    cB  = (cB + 1 == 34) ? 0 : cB + 1;
    cB2 = (cB2 + 1 == 34) ? 0 : cB2 + 1;
    int sq = (quad ^ ((lr >> 1) & 3)) * 8;
    int nIter = K >> 5;                      // 34
    for (int it = 0; it < nIter; ++it) {
        int cur = it & 1;
        __syncthreads();
        if (it + 1 < nIter) {
            int k = (it + 1) << 5, nx = cur ^ 1;
            GLD16(Ag + k, At[nx] + l0); GLD16(Ag2 + k, At[nx] + l1);
            GLD16(Bb + cB * 32, Bt[nx] + l0);
            GLD16(Bb2 + cB2 * 32, Bt[nx] + l1);
            cB  = (cB + 1 == 34) ? 0 : cB + 1;
            cB2 = (cB2 + 1 == 34) ? 0 : cB2 + 1;
        }
        bf16x8 af[4], bfr[4];
#pragma unroll
        for (int i = 0; i < 4; ++i)
            af[i] = *(const bf16x8*)(At[cur] + (wm + i * 16 + lr) * 32 + sq);
#pragma unroll
        for (int j = 0; j < 4; ++j)
            bfr[j] = *(const bf16x8*)(Bt[cur] + (wn + j * 16 + lr) * 32 + sq);
#pragma unroll
        for (int i = 0; i < 4; ++i)
#pragma unroll
            for (int j = 0; j < 4; ++j)
                acc[i][j] = __builtin_amdgcn_mfma_f32_16x16x32_bf16(af[i], bfr[j], acc[i][j], 0, 0, 0);
    }
#pragma unroll
    for (int i = 0; i < 4; ++i) {
        int rowb = row0 + wm + i * 16 + quad * 4;
#pragma unroll
        for (int j = 0; j < 4; ++j) {
            int col = col0 + wn + j * 16 + lr;     // even=gate, odd=up
#pragma unroll
            for (int r = 0; r < 4; ++r) {
                float own = acc[i][j][r];
                float oth = __shfl_xor(own, 1);
                if (!(lr & 1)) {
                    float sig = 1.0f / (1.0f + __expf(-own));
                    Hb[(size_t)(rowb + r) * KE3 + (col >> 1)] = f2bf(oth * own * sig);
                }
            }
        }
    }
}

// ------ GEMM 64x64, BK=64 dbuf, f32 + residual out (o, down) ----------------
template<int TAG>
__global__ __launch_bounds__(256) void gemm_s(
    const unsigned short* __restrict__ A, int lda,
    const unsigned short* __restrict__ B, int ldb, int K,
    float* __restrict__ Cf, int ldc, const float* __restrict__ Radd)
{
    __shared__ __align__(16) unsigned short At[2][64 * 64];
    __shared__ __align__(16) unsigned short Bt[2][64 * 64];
    int tid = threadIdx.x;
    int lane = tid & 63, wave = tid >> 6;
    int lr = lane & 15, quad = lane >> 4;
    int row0 = blockIdx.y * 64, col0 = blockIdx.x * 64;
    f32x4 acc[4];
    f32x4 zero = {0.f, 0.f, 0.f, 0.f};
#pragma unroll
    for (int j = 0; j < 4; ++j) acc[j] = zero;
    int rs = tid >> 3;
    int g8 = ((tid & 7) ^ (rs & 7)) * 8;
    const unsigned short* Ag  = A + (size_t)(row0 + rs) * lda + g8;
    const unsigned short* Ag2 = Ag + (size_t)32 * lda;
    const unsigned short* Bg  = B + (size_t)(col0 + rs) * ldb + g8;
    const unsigned short* Bg2 = Bg + (size_t)32 * ldb;
    int l0 = tid * 8, l1 = (tid + 256) * 8;
    GLD16(Ag, At[0] + l0); GLD16(Ag2, At[0] + l1);
    GLD16(Bg, Bt[0] + l0); GLD16(Bg2, Bt[0] + l1);
    int c0 = (quad ^ (lr & 7)) * 8;
    int c1 = ((4 + quad) ^ (lr & 7)) * 8;
    int nIter = K >> 6;
    for (int it = 0; it < nIter; ++it) {
        int cur = it & 1;
        __syncthreads();
        if (it + 1 < nIter) {
            int k = (it + 1) << 6, nx = cur ^ 1;
            GLD16(Ag + k, At[nx] + l0); GLD16(Ag2 + k, At[nx] + l1);
            GLD16(Bg + k, Bt[nx] + l0); GLD16(Bg2 + k, Bt[nx] + l1);
        }
        const unsigned short* arow = At[cur] + (wave * 16 + lr) * 64;
        bf16x8 a0 = *(const bf16x8*)(arow + c0);
        bf16x8 a1 = *(const bf16x8*)(arow + c1);
        bf16x8 b0[4], b1[4];
#pragma unroll
        for (int j = 0; j < 4; ++j) {
            const unsigned short* brow = Bt[cur] + (j * 16 + lr) * 64;
            b0[j] = *(const bf16x8*)(brow + c0);
            b1[j] = *(const bf16x8*)(brow + c1);
        }
#pragma unroll
        for (int j = 0; j < 4; ++j) {
            acc[j] = __builtin_amdgcn_mfma_f32_16x16x32_bf16(a0, b0[j], acc[j], 0, 0, 0);
            acc[j] = __builtin_amdgcn_mfma_f32_16x16x32_bf16(a1, b1[j], acc[j], 0, 0, 0);
        }
    }
    int rowb = row0 + wave * 16 + quad * 4;
#pragma unroll
    for (int j = 0; j < 4; ++j) {
        int col = col0 + j * 16 + lr;
#pragma unroll
        for (int r = 0; r < 4; ++r) {
            size_t o = (size_t)(rowb + r) * ldc + col;
            Cf[o] = acc[j][r] + Radd[o];
        }
    }
}

// -------- fused rope(q) + rope+fragment-pack(K) + fragment-pack(V) ----------
__global__ __launch_bounds__(256) void rope_pack(
    const unsigned short* __restrict__ qkv,
    const float* __restrict__ cosT, const float* __restrict__ sinT,
    const int* __restrict__ pos,
    unsigned short* __restrict__ qb, unsigned short* __restrict__ kpk,
    unsigned short* __restrict__ vpk)
{
    int b = blockIdx.x, tid = threadIdx.x;
    if (b < 8192) {                              // Q rope (coalesced write)
        int idx = b * 256 + tid;                 // over 2048*1024
        int s = idx >> 10, col = idx & 1023, d = col & 63;
        int p = pos[s];
        float c = cosT[p * 64 + d], sn = sinT[p * 64 + d];
        int partner = (d < 32) ? (col + 32) : (col - 32);
        float sgn = (d < 32) ? -1.f : 1.f;
        const unsigned short* row = qkv + (size_t)s * NQKV;
        float q = bf2f(row[col]), q2 = bf2f(row[partner]);
        qb[idx] = f2bf((q * c + sgn * q2 * sn) * 0.125f);
    } else if (b < 9216) {                       // K rope + pack, 16B/thread
        int g = (b - 8192) * 256 + tid;          // 0..262143
        int lr = g & 15, quad = (g >> 4) & 3, cch = (g >> 6) & 1;
        int t = (g >> 7) & 127, h = g >> 14;
        int s = t * 16 + lr;
        int p = pos[s];
        int d0 = cch * 32 + quad * 8;
        const unsigned short* krow = qkv + (size_t)s * NQKV + Dm + h * 64;
        uint4 kv8 = *(const uint4*)(krow + d0);
        uint4 kp8 = *(const uint4*)(krow + ((d0 + 32) & 63));
        float sgn = (d0 < 32) ? -1.f : 1.f;
        const float* cp = cosT + p * 64 + d0;
        const float* sp = sinT + p * 64 + d0;
        const unsigned short* ke = (const unsigned short*)&kv8;
        const unsigned short* pe = (const unsigned short*)&kp8;
        alignas(16) unsigned short out[8];
#pragma unroll
        for (int e = 0; e < 8; ++e)
            out[e] = f2bf(bf2f(ke[e]) * cp[e] + sgn * bf2f(pe[e]) * sp[e]);
        *(uint4*)(kpk + (size_t)g * 8) = *(uint4*)out;
    } else {                                     // V pack, 16B/thread
        int g = (b - 9216) * 256 + tid;          // 0..262143
        int lrr = g & 15, quad = (g >> 4) & 3, kk = (g >> 6) & 3;
        int j = (g >> 8) & 3, kt = (g >> 10) & 15, h = g >> 14;
        int d = j * 16 + lrr;
        int sbase = kt * 128 + kk * 32 + quad * 8;
        alignas(16) unsigned short out[8];
#pragma unroll
        for (int e = 0; e < 8; ++e)
            out[e] = qkv[(size_t)(sbase + e) * NQKV + 2048 + h * 64 + d];
        *(uint4*)(vpk + (size_t)g * 8) = *(uint4*)out;
    }
}

// ------------- flash attention: packed frags, no-max softmax ----------------
__global__ __launch_bounds__(256) void attn(
    const unsigned short* __restrict__ qb, const unsigned short* __restrict__ kpk,
    const unsigned short* __restrict__ vpk, unsigned short* __restrict__ ob)
{
    __shared__ __align__(16) unsigned short Ps[4][16 * 136];
    int tid = threadIdx.x;
    int lane = tid & 63, wave = tid >> 6;
    int lr = lane & 15, quad = lane >> 4;
    int idx = blockIdx.x;
    int t_ = idx >> 4;
    int qt = (idx < 256) ? (31 - t_) : (t_ - 16);
    int h = idx & 15;
    int r0 = qt * 64 + wave * 16;
    const unsigned short* qp = qb + (size_t)(r0 + lr) * Dm + h * 64 + quad * 8;
    bf16x8 qf0 = *(const bf16x8*)qp;
    bf16x8 qf1 = *(const bf16x8*)(qp + 32);
    const unsigned short* kpb = kpk + (size_t)h * 128 * 1024 + lane * 8;
    const unsigned short* vpb = vpk + (size_t)h * 16 * 16 * 512 + lane * 8;
    f32x4 zero = {0.f, 0.f, 0.f, 0.f};
    f32x4 oacc[4];
#pragma unroll
    for (int j = 0; j < 4; ++j) oacc[j] = zero;
    float lrow[4] = {0.f, 0.f, 0.f, 0.f};
    int ntile = (qt * 64 + 191) >> 7;

    for (int kt = 0; kt < ntile; ++kt) {
        int k0 = kt << 7;
        f32x4 sf[8];
#pragma unroll
        for (int jj = 0; jj < 8; ++jj) {
            const unsigned short* kp = kpb + (size_t)(kt * 8 + jj) * 1024;
            bf16x8 kf0 = *(const bf16x8*)kp;
            bf16x8 kf1 = *(const bf16x8*)(kp + 512);
            f32x4 z = zero;
            z = __builtin_amdgcn_mfma_f32_16x16x32_bf16(qf0, kf0, z, 0, 0, 0);
            z = __builtin_amdgcn_mfma_f32_16x16x32_bf16(qf1, kf1, z, 0, 0, 0);
            sf[jj] = z;
        }
        bf16x8 vf[4][4];
#pragma unroll
        for (int j = 0; j < 4; ++j)
#pragma unroll
            for (int kk = 0; kk < 4; ++kk)
                vf[j][kk] = *(const bf16x8*)(vpb + (size_t)((kt * 4 + j) * 4 + kk) * 512);
        if (kt == ntile - 1) {
#pragma unroll
            for (int jj = 0; jj < 8; ++jj)
#pragma unroll
                for (int r = 0; r < 4; ++r)
                    if (k0 + jj * 16 + lr > r0 + quad * 4 + r)
                        sf[jj][r] = -1e30f;
        }
#pragma unroll
        for (int jj = 0; jj < 8; ++jj)
#pragma unroll
            for (int r = 0; r < 4; ++r) {
                float p = __expf(sf[jj][r]);
                sf[jj][r] = p;
                lrow[r] += p;
            }
#pragma unroll
        for (int jj = 0; jj < 8; ++jj)
#pragma unroll
            for (int r = 0; r < 4; ++r)
                Ps[wave][(quad * 4 + r) * 136 + jj * 16 + lr] = truncbf(sf[jj][r]);
        bf16x8 pf[4];
#pragma unroll
        for (int kk = 0; kk < 4; ++kk)
            pf[kk] = *(const bf16x8*)(&Ps[wave][lr * 136 + kk * 32 + quad * 8]);
#pragma unroll
        for (int j = 0; j < 4; ++j)
#pragma unroll
            for (int kk = 0; kk < 4; ++kk)
                oacc[j] = __builtin_amdgcn_mfma_f32_16x16x32_bf16(pf[kk], vf[j][kk], oacc[j], 0, 0, 0);
    }
#pragma unroll
    for (int r = 0; r < 4; ++r)
#pragma unroll
        for (int m = 1; m < 16; m <<= 1) lrow[r] += __shfl_xor(lrow[r], m);
#pragma unroll
    for (int r = 0; r < 4; ++r) {
        float inv = 1.0f / lrow[r];
        int row = r0 + quad * 4 + r;
#pragma unroll
        for (int j = 0; j < 4; ++j)
            ob[(size_t)row * KE2 + h * 64 + j * 16 + lr] = f2bf(oacc[j][r] * inv);
    }
}

// ---------------------------------------------------------------------------
extern "C" void kernel_launch(void* const* d_in, const int* in_sizes, int n_in,
                              void* d_out, int out_size, void* d_ws, size_t ws_size,
                              hipStream_t stream)
{
    const float* x    = (const float*)d_in[0];
    const float* nw1  = (const float*)d_in[1];
    const float* nw2  = (const float*)d_in[2];
    const float* cosT = (const float*)d_in[3];
    const float* sinT = (const float*)d_in[4];
    const int*   pos  = (const int*)d_in[5];
    const int   *qc = (const int*)d_in[6],  *kc = (const int*)d_in[10],
                *vc = (const int*)d_in[14], *oc = (const int*)d_in[18],
                *gc = (const int*)d_in[22], *uc = (const int*)d_in[26],
                *dc = (const int*)d_in[30];
    const float *qa = (const float*)d_in[7],  *ka = (const float*)d_in[11],
                *va = (const float*)d_in[15], *oa = (const float*)d_in[19],
                *ga = (const float*)d_in[23], *ua = (const float*)d_in[27],
                *da = (const float*)d_in[31];
    const float *qla = (const float*)d_in[8],  *kla = (const float*)d_in[12],
                *vla = (const float*)d_in[16], *ola = (const float*)d_in[20],
                *gla = (const float*)d_in[24], *ula = (const float*)d_in[28],
                *dla = (const float*)d_in[32];
    const float *qlb = (const float*)d_in[9],  *klb = (const float*)d_in[13],
                *vlb = (const float*)d_in[17], *olb = (const float*)d_in[21],
                *glb = (const float*)d_in[25], *ulb = (const float*)d_in[29],
                *dlb = (const float*)d_in[33];

    // workspace (peak ~64.3 MB)
    // Wq+Wo overlay hb region (dead until gemm_gu); Wgu in the old W slot;
    // Wd in its own tail. x1 overlays qbf+kpk (dead after attn).
    char* ws = (char*)d_ws;
    unsigned short* h    = (unsigned short*)(ws + 0);          // [2048,1088]
    unsigned short* Wgu  = (unsigned short*)(ws + 4456448);    // [5632,1088] 12.25 MB
    unsigned short* qkv  = (unsigned short*)(ws + 16711680);   // [2048,3072]
    unsigned short* qbf  = (unsigned short*)(ws + 29294592);   // [2048,1024]
    unsigned short* kpk  = (unsigned short*)(ws + 33488896);   // 4 MB
    unsigned short* vpk  = (unsigned short*)(ws + 37683200);   // 4 MB
    unsigned short* obf  = (unsigned short*)(ws + 41877504);   // [2048,1088]
    float*          x1   = (float*)(ws + 29294592);            // overlays qbf+kpk
    unsigned short* hb   = (unsigned short*)(ws + 46333952);   // [2048,2880] 11.8 MB
    unsigned short* Wq   = (unsigned short*)(ws + 46333952);   // [3072,1088] 6.68 MB (alias hb)
    unsigned short* Wo   = (unsigned short*)(ws + 53022720);   // [1024,1088] 2.23 MB (alias hb)
    unsigned short* lapk = (unsigned short*)(ws + 58130432);   // 280 x 1KB
    unsigned short* Wd   = (unsigned short*)(ws + 58425344);   // [1024,2880] 5.9 MB
    float* outp = (float*)d_out;

    // ---- all weight prep in one launch (lora frags + 4 dequants) ----
    prep_weights<<<6678, 256, 0, stream>>>(
        qc, kc, vc, oc, gc, uc, dc, qa, ka, va, oa, ga, ua, da,
        qla, kla, vla, ola, gla, ula, dla, qlb, klb, vlb, olb, glb, ulb, dlb,
        lapk, Wq, Wo, Wgu, Wd);
    // ---- attention block ----
    rmsnorm_ext<<<Sq, 256, 0, stream>>>(x, nw1, h, KE1);
    lora_mfma<3><<<128, 256, 0, stream>>>(h, KE1, Dm, lapk, 0, 32, 64, 1024, 0, 0);
    gemm128<<<dim3(NQKV / 128, Sq / 128), 256, 0, stream>>>(h, KE1, Wq, KE1, KE1, qkv, NQKV);
    rope_pack<<<10240, 256, 0, stream>>>(qkv, cosT, sinT, pos, qbf, kpk, vpk);
    attn<<<512, 256, 0, stream>>>(qbf, kpk, vpk, obf);
    lora_mfma<1><<<128, 256, 0, stream>>>(obf, KE2, Dm, lapk, 96, 0, 0, 1024, 1040, 16);
    gemm_s<0><<<dim3(Dm / 64, Sq / 64), 256, 0, stream>>>(obf, KE2, Wo, KE2, KE2, x1, Dm, x);
    // ---- MLP block ----
    rmsnorm_ext<<<Sq, 256, 0, stream>>>(x1, nw2, h, KE1);
    lora_mfma<2><<<128, 256, 0, stream>>>(h, KE1, Dm, lapk, 128, 160, 0, 1024, 0, 0);
    gemm_gu<<<dim3(NGU / 128, Sq / 128), 256, 0, stream>>>(h, KE1, Wgu, LGW, LGW, hb);
    lora_mfma<1><<<128, 256, 0, stream>>>(hb, KE3, Fm, lapk, 192, 0, 0, 2816, 2832, 16);
    gemm_s<1><<<dim3(Dm / 64, Sq / 64), 256, 0, stream>>>(hb, KE3, Wd, KE3, KE3, outp, Dm, x1);
}

// Round 19
// 330.677 us; speedup vs baseline: 1.0852x; 1.0320x over previous
//
#include <hip/hip_runtime.h>
#include <stdint.h>

// ---------------------------------------------------------------------------
// MixedSparseSingleLayerWithGate: NF4-dequant QLoRA transformer layer, MI355X.
// R19 = R18 + (a) Q-rope fused into attn (in-register: partner halves d/d+32
// are exactly the qf0/qf1 fragments) -> qbf buffer eliminated, rope_pack
// shrinks 10240->2048 blocks; (b) rmsnorm#1 folded into prep_weights.
// 12 dispatches total. All other kernels identical to R18.
// ---------------------------------------------------------------------------

#define Sq   2048
#define Dm   1024
#define Fm   2816
#define Hh   16
#define KE1  1088   // h & W_qkv stride / qkv & o reduction
#define KE2  1088   // obf & W_o stride
#define LGW  1088   // gate/up W stride (rotated rows), reduction K = 1088
#define KE3  2880   // hb & W_down stride / down reduction
#define NQKV 3072
#define NGU  5632

typedef short bf16x8 __attribute__((ext_vector_type(8)));
typedef float f32x4  __attribute__((ext_vector_type(4)));

__constant__ float NF4_LUT[16] = {
    -1.0f, -0.6961928009986877f, -0.5250730514526367f, -0.39491748809814453f,
    -0.28444138169288635f, -0.18477343022823334f, -0.09105003625154495f, 0.0f,
    0.07958029955625534f, 0.16093020141124725f, 0.24611230194568634f,
    0.33791524171829224f, 0.44070982933044434f, 0.5626170039176941f,
    0.7229568362236023f, 1.0f};

__device__ inline unsigned short f2bf(float f) {
    union { float f; uint32_t u; } v; v.f = f;
    uint32_t u = v.u;
    return (unsigned short)((u + 0x7FFFu + ((u >> 16) & 1u)) >> 16);
}
__device__ inline float bf2f(unsigned short h) {
    union { uint32_t u; float f; } v; v.u = ((uint32_t)h) << 16;
    return v.f;
}
__device__ inline unsigned short truncbf(float f) {
    union { float f; uint32_t u; } v; v.f = f;
    return (unsigned short)(v.u >> 16);
}

// async global->LDS, 16 B per lane; LDS dest = wave-uniform base + lane*16
#define GLD16(gp, lp)                                                         \
    __builtin_amdgcn_global_load_lds(                                         \
        (__attribute__((address_space(1))) void*)(uintptr_t)(gp),             \
        (__attribute__((address_space(3))) void*)(uint32_t)(uintptr_t)(lp),   \
        16, 0, 0)

// --------------------------- rmsnorm -> bf16 ext -----------------------------
__global__ __launch_bounds__(256) void rmsnorm_ext(
    const float* __restrict__ X, const float* __restrict__ W,
    unsigned short* Hout, int ldh)
{
    int s = blockIdx.x, tid = threadIdx.x;
    const float4 v = *(const float4*)(X + (size_t)s * Dm + tid * 4);
    float ss = v.x * v.x + v.y * v.y + v.z * v.z + v.w * v.w;
#pragma unroll
    for (int m = 1; m < 64; m <<= 1) ss += __shfl_xor(ss, m);
    __shared__ float red[4];
    int lane = tid & 63, wave = tid >> 6;
    if (lane == 0) red[wave] = ss;
    __syncthreads();
    float scale = rsqrtf((red[0] + red[1] + red[2] + red[3]) * (1.0f / Dm) + 1e-10f);
    const float4 w = *(const float4*)(W + tid * 4);
    alignas(8) unsigned short o[4];
    o[0] = f2bf(v.x * scale * w.x);
    o[1] = f2bf(v.y * scale * w.y);
    o[2] = f2bf(v.z * scale * w.z);
    o[3] = f2bf(v.w * scale * w.w);
    *(ushort4*)(Hout + (size_t)s * ldh + tid * 4) = *(ushort4*)o;
    if (tid < 64) Hout[(size_t)s * ldh + Dm + tid] = 0;   // zero 1024..1088
}

// ---------------- NF4 dequant helper (bf16, K-extended rows) ----------------
__device__ inline void dq_row8(const float* lut, const int* cod, const float* am,
                               const float* lb, int nr, int c8, int K, int Nlb,
                               int toff, unsigned short* out)
{
    if (c8 < K) {
        size_t base = (size_t)nr * K + c8;
        const int4* cp = (const int4*)(cod + base);
        int4 ca = cp[0], cb = cp[1];
        float a = am[base >> 6];
        out[0] = f2bf(lut[ca.x] * a); out[1] = f2bf(lut[ca.y] * a);
        out[2] = f2bf(lut[ca.z] * a); out[3] = f2bf(lut[ca.w] * a);
        out[4] = f2bf(lut[cb.x] * a); out[5] = f2bf(lut[cb.y] * a);
        out[6] = f2bf(lut[cb.z] * a); out[7] = f2bf(lut[cb.w] * a);
    } else {
        int r = c8 - toff;
#pragma unroll
        for (int i = 0; i < 8; ++i) out[i] = 0;
        if (r >= 0 && r < 16) {
#pragma unroll
            for (int i = 0; i < 8; ++i) out[i] = f2bf(lb[(size_t)(r + i) * Nlb + nr]);
        }
    }
}

// ---- merged prep: lora frags + dequants {qkv,o,gu(rot),down} + rmsnorm1 ----
// [0,70) lora | [70,1702) qkv | [1702,2246) o | [2246,5238) gu |
// [5238,6678) down | [6678,8726) rmsnorm1
__global__ __launch_bounds__(256) void prep_weights(
    const int* __restrict__ qc, const int* __restrict__ kc, const int* __restrict__ vc,
    const int* __restrict__ oc, const int* __restrict__ gc, const int* __restrict__ uc,
    const int* __restrict__ dc,
    const float* __restrict__ qa, const float* __restrict__ ka, const float* __restrict__ va,
    const float* __restrict__ oa, const float* __restrict__ ga, const float* __restrict__ ua,
    const float* __restrict__ da,
    const float* __restrict__ qla, const float* __restrict__ kla, const float* __restrict__ vla,
    const float* __restrict__ ola, const float* __restrict__ gla, const float* __restrict__ ula,
    const float* __restrict__ dla,
    const float* __restrict__ qlb, const float* __restrict__ klb, const float* __restrict__ vlb,
    const float* __restrict__ olb, const float* __restrict__ glb, const float* __restrict__ ulb,
    const float* __restrict__ dlb,
    const float* __restrict__ x, const float* __restrict__ nw1,
    unsigned short* __restrict__ lapk, unsigned short* __restrict__ Wq,
    unsigned short* __restrict__ Wo, unsigned short* __restrict__ Wgu,
    unsigned short* __restrict__ Wd, unsigned short* __restrict__ h)
{
    int b = blockIdx.x, tid = threadIdx.x;
    if (b >= 6678) {                             // ---- rmsnorm #1 -----------
        int s = b - 6678;
        const float4 v = *(const float4*)(x + (size_t)s * Dm + tid * 4);
        float ss = v.x * v.x + v.y * v.y + v.z * v.z + v.w * v.w;
#pragma unroll
        for (int m = 1; m < 64; m <<= 1) ss += __shfl_xor(ss, m);
        __shared__ float red[4];
        int lane = tid & 63, wave = tid >> 6;
        if (lane == 0) red[wave] = ss;
        __syncthreads();
        float scale = rsqrtf((red[0] + red[1] + red[2] + red[3]) * (1.0f / Dm) + 1e-10f);
        const float4 w = *(const float4*)(nw1 + tid * 4);
        alignas(8) unsigned short o[4];
        o[0] = f2bf(v.x * scale * w.x);
        o[1] = f2bf(v.y * scale * w.y);
        o[2] = f2bf(v.z * scale * w.z);
        o[3] = f2bf(v.w * scale * w.w);
        *(ushort4*)(h + (size_t)s * KE1 + tid * 4) = *(ushort4*)o;
        if (tid < 64) h[(size_t)s * KE1 + Dm + tid] = 0;
        return;
    }
    if (b < 70) {                                // ---- lora fragment pack ----
        int chunk = b * 4 + (tid >> 6);
        int lane = tid & 63;
        int lr = lane & 15, quad = lane >> 4;
        const float* la;
        int lc;
        if (chunk < 192) {
            int m = chunk >> 5; lc = chunk & 31;
            la = (m == 0) ? qla : (m == 1) ? kla : (m == 2) ? vla
               : (m == 3) ? ola : (m == 4) ? gla : ula;
        } else {
            la = dla; lc = chunk - 192;
        }
        alignas(16) unsigned short out[8];
#pragma unroll
        for (int e = 0; e < 8; ++e)
            out[e] = f2bf(la[(size_t)(lc * 32 + quad * 8 + e) * 16 + lr]);
        *(uint4*)(lapk + (size_t)chunk * 512 + lane * 8) = *(uint4*)out;
        return;
    }
    __shared__ float lut[16];
    if (tid < 16) lut[tid] = NF4_LUT[tid];
    __syncthreads();
    if (b < 1702) {                              // ---- dequant qkv ----------
        int idx = (b - 70) * 256 + tid;          // 3072*136
        int n = idx / 136;
        int c8 = (idx - n * 136) * 8;
        int seg = n >> 10, nr = n & 1023;
        const int* cod   = (seg == 0) ? qc : (seg == 1) ? kc : vc;
        const float* am  = (seg == 0) ? qa : (seg == 1) ? ka : va;
        const float* lb  = (seg == 0) ? qlb : (seg == 1) ? klb : vlb;
        int toff = 1024 + (seg << 4);
        alignas(16) unsigned short out[8];
        dq_row8(lut, cod, am, lb, nr, c8, 1024, 1024, toff, out);
        *(uint4*)(Wq + (size_t)n * KE1 + c8) = *(uint4*)out;
    } else if (b < 2246) {                       // ---- dequant o ------------
        int idx = (b - 1702) * 256 + tid;        // 1024*136
        int n = idx / 136;
        int c8 = (idx - n * 136) * 8;
        alignas(16) unsigned short out[8];
        dq_row8(lut, oc, oa, olb, n, c8, 1024, Dm, 1024, out);
        *(uint4*)(Wo + (size_t)n * KE2 + c8) = *(uint4*)out;
    } else if (b < 5238) {                       // ---- dequant gu (rotated) -
        int idx = (b - 2246) * 256 + tid;        // 5632*136
        int n = idx / 136;
        int v8 = idx - n * 136;
        int m = n >> 1, mat = n & 1;
        const int* cod  = mat ? uc : gc;
        const float* am = mat ? ua : ga;
        const float* lb = mat ? ulb : glb;
        int toff = 1024 + (mat << 4);
        alignas(16) unsigned short out[8];
        dq_row8(lut, cod, am, lb, m, v8 * 8, 1024, Fm, toff, out);
        int ch = v8 >> 2, sub = v8 & 3;
        int ph = ch + (n % 34); if (ph >= 34) ph -= 34;
        *(uint4*)(Wgu + (size_t)n * LGW + ph * 32 + sub * 8) = *(uint4*)out;
    } else {                                     // ---- dequant down ---------
        int idx = (b - 5238) * 256 + tid;        // 1024*360
        int n = idx / 360;
        if (n >= Dm) return;
        int c8 = (idx - n * 360) * 8;
        alignas(16) unsigned short out[8];
        dq_row8(lut, dc, da, dlb, n, c8, 2816, Dm, 2816, out);
        *(uint4*)(Wd + (size_t)n * KE3 + c8) = *(uint4*)out;
    }
}

// -------- T = A @ la via MFMA; 16-row strips, 4-way wave K-split ------------
template<int NM>
__global__ __launch_bounds__(256) void lora_mfma(
    unsigned short* Aext, int lda, int K,
    const unsigned short* __restrict__ lapk, int c0, int c1, int c2,
    int toff, int zoff, int zn)
{
    int tid = threadIdx.x;
    int lane = tid & 63, wave = tid >> 6;
    int lr = lane & 15, quad = lane >> 4;
    int r0 = blockIdx.x * 16;
    int nc4 = K >> 7;                       // chunks per wave
    int gc0 = wave * nc4;
    const unsigned short* Ab = Aext + (size_t)(r0 + lr) * lda + quad * 8;
    int cb[3] = {c0, c1, c2};
    f32x4 zero = {0.f, 0.f, 0.f, 0.f};
    f32x4 acc[NM];
#pragma unroll
    for (int m = 0; m < NM; ++m) acc[m] = zero;
    for (int cc = 0; cc < nc4; ++cc) {
        int gc = gc0 + cc;
        bf16x8 af = *(const bf16x8*)(Ab + gc * 32);
#pragma unroll
        for (int m = 0; m < NM; ++m) {
            bf16x8 bf = *(const bf16x8*)(lapk + (size_t)(cb[m] + gc) * 512 + lane * 8);
            acc[m] = __builtin_amdgcn_mfma_f32_16x16x32_bf16(af, bf, acc[m], 0, 0, 0);
        }
    }
    __shared__ float red[3][NM * 64 * 4];
    if (wave > 0) {
#pragma unroll
        for (int m = 0; m < NM; ++m)
#pragma unroll
            for (int r = 0; r < 4; ++r)
                red[wave - 1][(m * 64 + lane) * 4 + r] = acc[m][r];
    }
    __syncthreads();
    if (wave == 0) {
#pragma unroll
        for (int m = 0; m < NM; ++m)
#pragma unroll
            for (int r = 0; r < 4; ++r)
                acc[m][r] += red[0][(m * 64 + lane) * 4 + r]
                           + red[1][(m * 64 + lane) * 4 + r]
                           + red[2][(m * 64 + lane) * 4 + r];
#pragma unroll
        for (int r = 0; r < 4; ++r) {
            int row = r0 + quad * 4 + r;
#pragma unroll
            for (int m = 0; m < NM; ++m)
                Aext[(size_t)row * lda + toff + m * 16 + lr] = f2bf(acc[m][r]);
        }
        if (zn > 0) {
            int row = r0 + lr, j0 = quad * 4;
            for (int j = j0; j < zn; j += 64) {
                alignas(8) unsigned short z4[4] = {0, 0, 0, 0};
                *(ushort4*)(Aext + (size_t)row * lda + zoff + j) = *(ushort4*)z4;
            }
        }
    }
}

// ------------------- GEMM 128x128, dbuf, bf16-out (qkv) ---------------------
__global__ __launch_bounds__(256) void gemm128(
    const unsigned short* __restrict__ A, int lda,
    const unsigned short* __restrict__ B, int ldb, int K,
    unsigned short* __restrict__ Cb, int ldc)
{
    __shared__ __align__(16) unsigned short At[2][128 * 32];
    __shared__ __align__(16) unsigned short Bt[2][128 * 32];
    int tid = threadIdx.x;
    int lane = tid & 63, wave = tid >> 6;
    int lr = lane & 15, quad = lane >> 4;
    int wm = (wave >> 1) * 64, wn = (wave & 1) * 64;
    int row0 = blockIdx.y * 128, col0 = blockIdx.x * 128;
    f32x4 acc[4][4];
    f32x4 zero = {0.f, 0.f, 0.f, 0.f};
#pragma unroll
    for (int i = 0; i < 4; ++i)
#pragma unroll
        for (int j = 0; j < 4; ++j) acc[i][j] = zero;
    int sw = ((tid & 3) ^ ((tid >> 3) & 3)) * 8;
    const unsigned short* Ag  = A + (size_t)(row0 + (tid >> 2)) * lda + sw;
    const unsigned short* Ag2 = Ag + (size_t)64 * lda;
    const unsigned short* Bg  = B + (size_t)(col0 + (tid >> 2)) * ldb + sw;
    const unsigned short* Bg2 = Bg + (size_t)64 * ldb;
    int l0 = tid * 8, l1 = (tid + 256) * 8;
    GLD16(Ag, At[0] + l0); GLD16(Ag2, At[0] + l1);
    GLD16(Bg, Bt[0] + l0); GLD16(Bg2, Bt[0] + l1);
    int sq = (quad ^ ((lr >> 1) & 3)) * 8;
    int nIter = K >> 5;
    for (int it = 0; it < nIter; ++it) {
        int cur = it & 1;
        __syncthreads();
        if (it + 1 < nIter) {
            int k = (it + 1) << 5, nx = cur ^ 1;
            GLD16(Ag + k, At[nx] + l0); GLD16(Ag2 + k, At[nx] + l1);
            GLD16(Bg + k, Bt[nx] + l0); GLD16(Bg2 + k, Bt[nx] + l1);
        }
        bf16x8 af[4], bfr[4];
#pragma unroll
        for (int i = 0; i < 4; ++i)
            af[i] = *(const bf16x8*)(At[cur] + (wm + i * 16 + lr) * 32 + sq);
#pragma unroll
        for (int j = 0; j < 4; ++j)
            bfr[j] = *(const bf16x8*)(Bt[cur] + (wn + j * 16 + lr) * 32 + sq);
#pragma unroll
        for (int i = 0; i < 4; ++i)
#pragma unroll
            for (int j = 0; j < 4; ++j)
                acc[i][j] = __builtin_amdgcn_mfma_f32_16x16x32_bf16(af[i], bfr[j], acc[i][j], 0, 0, 0);
    }
#pragma unroll
    for (int i = 0; i < 4; ++i) {
        int rowb = row0 + wm + i * 16 + quad * 4;
#pragma unroll
        for (int j = 0; j < 4; ++j) {
            int col = col0 + wn + j * 16 + lr;
#pragma unroll
            for (int r = 0; r < 4; ++r)
                Cb[(size_t)(rowb + r) * ldc + col] = f2bf(acc[i][j][r]);
        }
    }
}

// --- GEMM 128x128, dbuf, SwiGLU epilogue (gate/up); B rows ROTATED ----------
__global__ __launch_bounds__(256) void gemm_gu(
    const unsigned short* __restrict__ A, int lda,
    const unsigned short* __restrict__ B, int ldb, int K,
    unsigned short* __restrict__ Hb)
{
    __shared__ __align__(16) unsigned short At[2][128 * 32];
    __shared__ __align__(16) unsigned short Bt[2][128 * 32];
    int tid = threadIdx.x;
    int lane = tid & 63, wave = tid >> 6;
    int lr = lane & 15, quad = lane >> 4;
    int wm = (wave >> 1) * 64, wn = (wave & 1) * 64;
    int row0 = blockIdx.y * 128, col0 = blockIdx.x * 128;
    f32x4 acc[4][4];
    f32x4 zero = {0.f, 0.f, 0.f, 0.f};
#pragma unroll
    for (int i = 0; i < 4; ++i)
#pragma unroll
        for (int j = 0; j < 4; ++j) acc[i][j] = zero;
    int sw = ((tid & 3) ^ ((tid >> 3) & 3)) * 8;
    const unsigned short* Ag  = A + (size_t)(row0 + (tid >> 2)) * lda + sw;
    const unsigned short* Ag2 = Ag + (size_t)64 * lda;
    int rB  = col0 + (tid >> 2);
    const unsigned short* Bb  = B + (size_t)rB * ldb + sw;
    const unsigned short* Bb2 = B + (size_t)(rB + 64) * ldb + sw;
    int cB  = rB % 34;
    int cB2 = (rB + 64) % 34;
    int l0 = tid * 8, l1 = (tid + 256) * 8;
    GLD16(Ag, At[0] + l0); GLD16(Ag2, At[0] + l1);
    GLD16(Bb + cB * 32, Bt[0] + l0);
    GLD16(Bb2 + cB2 * 32, Bt[0] + l1);
    cB  = (cB + 1 == 34) ? 0 : cB + 1;
    cB2 = (cB2 + 1 == 34) ? 0 : cB2 + 1;
    int sq = (quad ^ ((lr >> 1) & 3)) * 8;
    int nIter = K >> 5;                      // 34
    for (int it = 0; it < nIter; ++it) {
        int cur = it & 1;
        __syncthreads();
        if (it + 1 < nIter) {
            int k = (it + 1) << 5, nx = cur ^ 1;
            GLD16(Ag + k, At[nx] + l0); GLD16(Ag2 + k, At[nx] + l1);
            GLD16(Bb + cB * 32, Bt[nx] + l0);
            GLD16(Bb2 + cB2 * 32, Bt[nx] + l1);
            cB  = (cB + 1 == 34) ? 0 : cB + 1;
            cB2 = (cB2 + 1 == 34) ? 0 : cB2 + 1;
        }
        bf16x8 af[4], bfr[4];
#pragma unroll
        for (int i = 0; i < 4; ++i)
            af[i] = *(const bf16x8*)(At[cur] + (wm + i * 16 + lr) * 32 + sq);
#pragma unroll
        for (int j = 0; j < 4; ++j)
            bfr[j] = *(const bf16x8*)(Bt[cur] + (wn + j * 16 + lr) * 32 + sq);
#pragma unroll
        for (int i = 0; i < 4; ++i)
#pragma unroll
            for (int j = 0; j < 4; ++j)
                acc[i][j] = __builtin_amdgcn_mfma_f32_16x16x32_bf16(af[i], bfr[j], acc[i][j], 0, 0, 0);
    }
#pragma unroll
    for (int i = 0; i < 4; ++i) {
        int rowb = row0 + wm + i * 16 + quad * 4;
#pragma unroll
        for (int j = 0; j < 4; ++j) {
            int col = col0 + wn + j * 16 + lr;     // even=gate, odd=up
#pragma unroll
            for (int r = 0; r < 4; ++r) {
                float own = acc[i][j][r];
                float oth = __shfl_xor(own, 1);
                if (!(lr & 1)) {
                    float sig = 1.0f / (1.0f + __expf(-own));
                    Hb[(size_t)(rowb + r) * KE3 + (col >> 1)] = f2bf(oth * own * sig);
                }
            }
        }
    }
}

// ------ GEMM 64x64, BK=64 dbuf, f32 + residual out (o, down) ----------------
template<int TAG>
__global__ __launch_bounds__(256) void gemm_s(
    const unsigned short* __restrict__ A, int lda,
    const unsigned short* __restrict__ B, int ldb, int K,
    float* __restrict__ Cf, int ldc, const float* __restrict__ Radd)
{
    __shared__ __align__(16) unsigned short At[2][64 * 64];
    __shared__ __align__(16) unsigned short Bt[2][64 * 64];
    int tid = threadIdx.x;
    int lane = tid & 63, wave = tid >> 6;
    int lr = lane & 15, quad = lane >> 4;
    int row0 = blockIdx.y * 64, col0 = blockIdx.x * 64;
    f32x4 acc[4];
    f32x4 zero = {0.f, 0.f, 0.f, 0.f};
#pragma unroll
    for (int j = 0; j < 4; ++j) acc[j] = zero;
    int rs = tid >> 3;
    int g8 = ((tid & 7) ^ (rs & 7)) * 8;
    const unsigned short* Ag  = A + (size_t)(row0 + rs) * lda + g8;
    const unsigned short* Ag2 = Ag + (size_t)32 * lda;
    const unsigned short* Bg  = B + (size_t)(col0 + rs) * ldb + g8;
    const unsigned short* Bg2 = Bg + (size_t)32 * ldb;
    int l0 = tid * 8, l1 = (tid + 256) * 8;
    GLD16(Ag, At[0] + l0); GLD16(Ag2, At[0] + l1);
    GLD16(Bg, Bt[0] + l0); GLD16(Bg2, Bt[0] + l1);
    int c0 = (quad ^ (lr & 7)) * 8;
    int c1 = ((4 + quad) ^ (lr & 7)) * 8;
    int nIter = K >> 6;
    for (int it = 0; it < nIter; ++it) {
        int cur = it & 1;
        __syncthreads();
        if (it + 1 < nIter) {
            int k = (it + 1) << 6, nx = cur ^ 1;
            GLD16(Ag + k, At[nx] + l0); GLD16(Ag2 + k, At[nx] + l1);
            GLD16(Bg + k, Bt[nx] + l0); GLD16(Bg2 + k, Bt[nx] + l1);
        }
        const unsigned short* arow = At[cur] + (wave * 16 + lr) * 64;
        bf16x8 a0 = *(const bf16x8*)(arow + c0);
        bf16x8 a1 = *(const bf16x8*)(arow + c1);
        bf16x8 b0[4], b1[4];
#pragma unroll
        for (int j = 0; j < 4; ++j) {
            const unsigned short* brow = Bt[cur] + (j * 16 + lr) * 64;
            b0[j] = *(const bf16x8*)(brow + c0);
            b1[j] = *(const bf16x8*)(brow + c1);
        }
#pragma unroll
        for (int j = 0; j < 4; ++j) {
            acc[j] = __builtin_amdgcn_mfma_f32_16x16x32_bf16(a0, b0[j], acc[j], 0, 0, 0);
            acc[j] = __builtin_amdgcn_mfma_f32_16x16x32_bf16(a1, b1[j], acc[j], 0, 0, 0);
        }
    }
    int rowb = row0 + wave * 16 + quad * 4;
#pragma unroll
    for (int j = 0; j < 4; ++j) {
        int col = col0 + j * 16 + lr;
#pragma unroll
        for (int r = 0; r < 4; ++r) {
            size_t o = (size_t)(rowb + r) * ldc + col;
            Cf[o] = acc[j][r] + Radd[o];
        }
    }
}

// --------- rope+fragment-pack(K) + fragment-pack(V) (Q handled in attn) -----
__global__ __launch_bounds__(256) void rope_pack(
    const unsigned short* __restrict__ qkv,
    const float* __restrict__ cosT, const float* __restrict__ sinT,
    const int* __restrict__ pos,
    unsigned short* __restrict__ kpk, unsigned short* __restrict__ vpk)
{
    int b = blockIdx.x, tid = threadIdx.x;
    if (b < 1024) {                              // K rope + pack, 16B/thread
        int g = b * 256 + tid;                   // 0..262143
        int lr = g & 15, quad = (g >> 4) & 3, cch = (g >> 6) & 1;
        int t = (g >> 7) & 127, h = g >> 14;
        int s = t * 16 + lr;
        int p = pos[s];
        int d0 = cch * 32 + quad * 8;
        const unsigned short* krow = qkv + (size_t)s * NQKV + Dm + h * 64;
        uint4 kv8 = *(const uint4*)(krow + d0);
        uint4 kp8 = *(const uint4*)(krow + ((d0 + 32) & 63));
        float sgn = (d0 < 32) ? -1.f : 1.f;
        const float* cp = cosT + p * 64 + d0;
        const float* sp = sinT + p * 64 + d0;
        const unsigned short* ke = (const unsigned short*)&kv8;
        const unsigned short* pe = (const unsigned short*)&kp8;
        alignas(16) unsigned short out[8];
#pragma unroll
        for (int e = 0; e < 8; ++e)
            out[e] = f2bf(bf2f(ke[e]) * cp[e] + sgn * bf2f(pe[e]) * sp[e]);
        *(uint4*)(kpk + (size_t)g * 8) = *(uint4*)out;
    } else {                                     // V pack, 16B/thread
        int g = (b - 1024) * 256 + tid;          // 0..262143
        int lrr = g & 15, quad = (g >> 4) & 3, kk = (g >> 6) & 3;
        int j = (g >> 8) & 3, kt = (g >> 10) & 15, h = g >> 14;
        int d = j * 16 + lrr;
        int sbase = kt * 128 + kk * 32 + quad * 8;
        alignas(16) unsigned short out[8];
#pragma unroll
        for (int e = 0; e < 8; ++e)
            out[e] = qkv[(size_t)(sbase + e) * NQKV + 2048 + h * 64 + d];
        *(uint4*)(vpk + (size_t)g * 8) = *(uint4*)out;
    }
}

// --- flash attention: in-register Q-rope, packed K/V frags, no-max softmax --
// Q read directly from qkv; rope partner of qf0 is qf1 (d <-> d+32).
__global__ __launch_bounds__(256) void attn(
    const unsigned short* __restrict__ qkv, const int* __restrict__ pos,
    const float* __restrict__ cosT, const float* __restrict__ sinT,
    const unsigned short* __restrict__ kpk, const unsigned short* __restrict__ vpk,
    unsigned short* __restrict__ ob)
{
    __shared__ __align__(16) unsigned short Ps[4][16 * 136];
    int tid = threadIdx.x;
    int lane = tid & 63, wave = tid >> 6;
    int lr = lane & 15, quad = lane >> 4;
    int idx = blockIdx.x;
    int t_ = idx >> 4;
    int qt = (idx < 256) ? (31 - t_) : (t_ - 16);
    int h = idx & 15;
    int r0 = qt * 64 + wave * 16;
    // ---- Q load + in-register rope (scale 1/8 folded) ----
    int qrow = r0 + lr;
    int p = pos[qrow];
    const unsigned short* qp = qkv + (size_t)qrow * NQKV + h * 64 + quad * 8;
    uint4 q0v = *(const uint4*)qp;          // d = quad*8 .. +7   (d < 32)
    uint4 q1v = *(const uint4*)(qp + 32);   // d+32
    const float* cp = cosT + p * 64 + quad * 8;
    const float* sp = sinT + p * 64 + quad * 8;
    const unsigned short* q0e = (const unsigned short*)&q0v;
    const unsigned short* q1e = (const unsigned short*)&q1v;
    alignas(16) unsigned short qo0[8], qo1[8];
#pragma unroll
    for (int e = 0; e < 8; ++e) {
        float a = bf2f(q0e[e]), bq = bf2f(q1e[e]);
        qo0[e] = f2bf((a * cp[e] - bq * sp[e]) * 0.125f);
        qo1[e] = f2bf((bq * cp[32 + e] + a * sp[32 + e]) * 0.125f);
    }
    bf16x8 qf0 = *(const bf16x8*)qo0;
    bf16x8 qf1 = *(const bf16x8*)qo1;
    const unsigned short* kpb = kpk + (size_t)h * 128 * 1024 + lane * 8;
    const unsigned short* vpb = vpk + (size_t)h * 16 * 16 * 512 + lane * 8;
    f32x4 zero = {0.f, 0.f, 0.f, 0.f};
    f32x4 oacc[4];
#pragma unroll
    for (int j = 0; j < 4; ++j) oacc[j] = zero;
    float lrow[4] = {0.f, 0.f, 0.f, 0.f};
    int ntile = (qt * 64 + 191) >> 7;

    for (int kt = 0; kt < ntile; ++kt) {
        int k0 = kt << 7;
        f32x4 sf[8];
#pragma unroll
        for (int jj = 0; jj < 8; ++jj) {
            const unsigned short* kp = kpb + (size_t)(kt * 8 + jj) * 1024;
            bf16x8 kf0 = *(const bf16x8*)kp;
            bf16x8 kf1 = *(const bf16x8*)(kp + 512);
            f32x4 z = zero;
            z = __builtin_amdgcn_mfma_f32_16x16x32_bf16(qf0, kf0, z, 0, 0, 0);
            z = __builtin_amdgcn_mfma_f32_16x16x32_bf16(qf1, kf1, z, 0, 0, 0);
            sf[jj] = z;
        }
        bf16x8 vf[4][4];
#pragma unroll
        for (int j = 0; j < 4; ++j)
#pragma unroll
            for (int kk = 0; kk < 4; ++kk)
                vf[j][kk] = *(const bf16x8*)(vpb + (size_t)((kt * 4 + j) * 4 + kk) * 512);
        if (kt == ntile - 1) {
#pragma unroll
            for (int jj = 0; jj < 8; ++jj)
#pragma unroll
                for (int r = 0; r < 4; ++r)
                    if (k0 + jj * 16 + lr > r0 + quad * 4 + r)
                        sf[jj][r] = -1e30f;
        }
#pragma unroll
        for (int jj = 0; jj < 8; ++jj)
#pragma unroll
            for (int r = 0; r < 4; ++r) {
                float pr = __expf(sf[jj][r]);
                sf[jj][r] = pr;
                lrow[r] += pr;
            }
#pragma unroll
        for (int jj = 0; jj < 8; ++jj)
#pragma unroll
            for (int r = 0; r < 4; ++r)
                Ps[wave][(quad * 4 + r) * 136 + jj * 16 + lr] = truncbf(sf[jj][r]);
        bf16x8 pf[4];
#pragma unroll
        for (int kk = 0; kk < 4; ++kk)
            pf[kk] = *(const bf16x8*)(&Ps[wave][lr * 136 + kk * 32 + quad * 8]);
#pragma unroll
        for (int j = 0; j < 4; ++j)
#pragma unroll
            for (int kk = 0; kk < 4; ++kk)
                oacc[j] = __builtin_amdgcn_mfma_f32_16x16x32_bf16(pf[kk], vf[j][kk], oacc[j], 0, 0, 0);
    }
#pragma unroll
    for (int r = 0; r < 4; ++r)
#pragma unroll
        for (int m = 1; m < 16; m <<= 1) lrow[r] += __shfl_xor(lrow[r], m);
#pragma unroll
    for (int r = 0; r < 4; ++r) {
        float inv = 1.0f / lrow[r];
        int row = r0 + quad * 4 + r;
#pragma unroll
        for (int j = 0; j < 4; ++j)
            ob[(size_t)row * KE2 + h * 64 + j * 16 + lr] = f2bf(oacc[j][r] * inv);
    }
}

// ---------------------------------------------------------------------------
extern "C" void kernel_launch(void* const* d_in, const int* in_sizes, int n_in,
                              void* d_out, int out_size, void* d_ws, size_t ws_size,
                              hipStream_t stream)
{
    const float* x    = (const float*)d_in[0];
    const float* nw1  = (const float*)d_in[1];
    const float* nw2  = (const float*)d_in[2];
    const float* cosT = (const float*)d_in[3];
    const float* sinT = (const float*)d_in[4];
    const int*   pos  = (const int*)d_in[5];
    const int   *qc = (const int*)d_in[6],  *kc = (const int*)d_in[10],
                *vc = (const int*)d_in[14], *oc = (const int*)d_in[18],
                *gc = (const int*)d_in[22], *uc = (const int*)d_in[26],
                *dc = (const int*)d_in[30];
    const float *qa = (const float*)d_in[7],  *ka = (const float*)d_in[11],
                *va = (const float*)d_in[15], *oa = (const float*)d_in[19],
                *ga = (const float*)d_in[23], *ua = (const float*)d_in[27],
                *da = (const float*)d_in[31];
    const float *qla = (const float*)d_in[8],  *kla = (const float*)d_in[12],
                *vla = (const float*)d_in[16], *ola = (const float*)d_in[20],
                *gla = (const float*)d_in[24], *ula = (const float*)d_in[28],
                *dla = (const float*)d_in[32];
    const float *qlb = (const float*)d_in[9],  *klb = (const float*)d_in[13],
                *vlb = (const float*)d_in[17], *olb = (const float*)d_in[21],
                *glb = (const float*)d_in[25], *ulb = (const float*)d_in[29],
                *dlb = (const float*)d_in[33];

    // workspace (peak ~64.3 MB); qbf eliminated (Q roped in attn)
    char* ws = (char*)d_ws;
    unsigned short* h    = (unsigned short*)(ws + 0);          // [2048,1088]
    unsigned short* Wgu  = (unsigned short*)(ws + 4456448);    // [5632,1088]
    unsigned short* qkv  = (unsigned short*)(ws + 16711680);   // [2048,3072]
    unsigned short* kpk  = (unsigned short*)(ws + 33488896);   // 4 MB
    unsigned short* vpk  = (unsigned short*)(ws + 37683200);   // 4 MB
    unsigned short* obf  = (unsigned short*)(ws + 41877504);   // [2048,1088]
    float*          x1   = (float*)(ws + 29294592);            // overlays dead tail of qkv region + kpk
    unsigned short* hb   = (unsigned short*)(ws + 46333952);   // [2048,2880]
    unsigned short* Wq   = (unsigned short*)(ws + 46333952);   // alias hb
    unsigned short* Wo   = (unsigned short*)(ws + 53022720);   // alias hb
    unsigned short* lapk = (unsigned short*)(ws + 58130432);   // 280 x 1KB
    unsigned short* Wd   = (unsigned short*)(ws + 58425344);   // [1024,2880]
    float* outp = (float*)d_out;

    // ---- weight prep + rmsnorm1 in one launch ----
    prep_weights<<<8726, 256, 0, stream>>>(
        qc, kc, vc, oc, gc, uc, dc, qa, ka, va, oa, ga, ua, da,
        qla, kla, vla, ola, gla, ula, dla, qlb, klb, vlb, olb, glb, ulb, dlb,
        x, nw1, lapk, Wq, Wo, Wgu, Wd, h);
    // ---- attention block ----
    lora_mfma<3><<<128, 256, 0, stream>>>(h, KE1, Dm, lapk, 0, 32, 64, 1024, 0, 0);
    gemm128<<<dim3(NQKV / 128, Sq / 128), 256, 0, stream>>>(h, KE1, Wq, KE1, KE1, qkv, NQKV);
    rope_pack<<<2048, 256, 0, stream>>>(qkv, cosT, sinT, pos, kpk, vpk);
    attn<<<512, 256, 0, stream>>>(qkv, pos, cosT, sinT, kpk, vpk, obf);
    lora_mfma<1><<<128, 256, 0, stream>>>(obf, KE2, Dm, lapk, 96, 0, 0, 1024, 1040, 16);
    gemm_s<0><<<dim3(Dm / 64, Sq / 64), 256, 0, stream>>>(obf, KE2, Wo, KE2, KE2, x1, Dm, x);
    // ---- MLP block ----
    rmsnorm_ext<<<Sq, 256, 0, stream>>>(x1, nw2, h, KE1);
    lora_mfma<2><<<128, 256, 0, stream>>>(h, KE1, Dm, lapk, 128, 160, 0, 1024, 0, 0);
    gemm_gu<<<dim3(NGU / 128, Sq / 128), 256, 0, stream>>>(h, KE1, Wgu, LGW, LGW, hb);
    lora_mfma<1><<<128, 256, 0, stream>>>(hb, KE3, Fm, lapk, 192, 0, 0, 2816, 2832, 16);
    gemm_s<1><<<dim3(Dm / 64, Sq / 64), 256, 0, stream>>>(hb, KE3, Wd, KE3, KE3, outp, Dm, x1);
}